// Round 12
// baseline (282.528 us; speedup 1.0000x reference)
//
#include <hip/hip_runtime.h>
#include <stdint.h>

// SelfAttentionV3 with mask-compaction. B=8, S=2048, D=1024.
// Valid rows (mask==1) are compacted per batch (nv, idx); projections, scores,
// softmax, PV run on nv_pad rows/cols only. Masked q-rows get
// out = (mean Xv)·Wv + bv exactly (uniform softmax over all 2048 rows).
// GEMM core R12: m201-faithful 8-phase loop — 16 MFMA/phase, reads-in-phase,
// 2 stages/phase before the barrier, SB;BAR;lgkmcnt(0);setprio;MFMA;BAR,
// branch-free steady loop + peeled final iteration, uniform vmcnt(4).

typedef unsigned short u16;
typedef __attribute__((ext_vector_type(8))) short short8;
typedef __attribute__((ext_vector_type(4))) float f32x4;

__device__ __forceinline__ u16 f2bf(float x) {
  unsigned u = __float_as_uint(x);
  return (u16)((u + 0x7FFFu + ((u >> 16) & 1u)) >> 16);  // RNE
}
__device__ __forceinline__ float bf2f(u16 h) {
  return __uint_as_float(((unsigned)h) << 16);
}

__device__ __forceinline__ void stage16(const void* g, void* l) {
  const __attribute__((address_space(1))) uint32_t* gp =
      (const __attribute__((address_space(1))) uint32_t*)(uintptr_t)g;
  __attribute__((address_space(3))) uint32_t* lp =
      (__attribute__((address_space(3))) uint32_t*)(uintptr_t)l;
  __builtin_amdgcn_global_load_lds(gp, lp, 16, 0, 0);
}

__device__ __forceinline__ short8 ld8(const char* p, int off) {
  return *(const short8*)(p + off);
}

// ---- mask prefix-scan: per batch -> idx list, nv, nvpad ----
__global__ __launch_bounds__(256) void maskscan(const int* __restrict__ mask,
                                                int* __restrict__ idxA,
                                                int* __restrict__ nvA,
                                                int* __restrict__ nvpadA) {
  const int b = blockIdx.x;
  const int t = threadIdx.x, lane = t & 63, w = t >> 6;
  const int* m = mask + b * 2048;
  int v[8], loc = 0;
#pragma unroll
  for (int i = 0; i < 8; ++i) { v[i] = m[t * 8 + i]; loc += v[i]; }
  int sc = loc;  // inclusive scan over 64 lanes
  for (int off = 1; off < 64; off <<= 1) {
    int n = __shfl_up(sc, off);
    if (lane >= off) sc += n;
  }
  __shared__ int wsum[4];
  if (lane == 63) wsum[w] = sc;
  __syncthreads();
  int woff = 0;
  for (int i = 0; i < w; ++i) woff += wsum[i];
  int pos = woff + sc - loc;  // exclusive prefix
#pragma unroll
  for (int i = 0; i < 8; ++i)
    if (v[i]) idxA[b * 2048 + (pos++)] = t * 8 + i;
  if (t == 255) {
    const int nv = woff + sc;
    nvA[b] = nv;
    nvpadA[b] = (nv + 255) & ~255;
  }
}

// ---- fused gather+convert for q,k,v (z selects input) ----
__global__ __launch_bounds__(256) void compact3(const float* __restrict__ Xq,
                                                const float* __restrict__ Xk,
                                                const float* __restrict__ Xv,
                                                const int* __restrict__ idxA,
                                                const int* __restrict__ nvA,
                                                u16* __restrict__ Oq,
                                                u16* __restrict__ Ok,
                                                u16* __restrict__ Ov) {
  const int b = blockIdx.y, j = blockIdx.x, z = blockIdx.z;
  if (j >= nvA[b]) return;
  const float* X = (z == 0) ? Xq : (z == 1) ? Xk : Xv;
  u16* out = (z == 0) ? Oq : (z == 1) ? Ok : Ov;
  const int src = idxA[b * 2048 + j];
  const float4* s = (const float4*)(X + ((size_t)b * 2048 + src) * 1024);
  ushort4* d = (ushort4*)(out + ((size_t)b * 2048 + j) * 1024);
  const float4 f = s[threadIdx.x];
  ushort4 o;
  o.x = f2bf(f.x); o.y = f2bf(f.y); o.z = f2bf(f.z); o.w = f2bf(f.w);
  d[threadIdx.x] = o;
}

// ---- column partial sums of Xv (all 2048 rows) ----
__global__ __launch_bounds__(256) void colpart(const float* __restrict__ X,
                                               float* __restrict__ partial) {
  const int b = blockIdx.x, dq = blockIdx.y, sck = blockIdx.z;
  const int d = dq * 256 + threadIdx.x;
  const float* p = X + ((size_t)b * 2048 + sck * 256) * 1024 + d;
  float s0 = 0, s1 = 0, s2 = 0, s3 = 0;
  for (int r = 0; r < 256; r += 4) {
    s0 += p[(size_t)(r + 0) * 1024];
    s1 += p[(size_t)(r + 1) * 1024];
    s2 += p[(size_t)(r + 2) * 1024];
    s3 += p[(size_t)(r + 3) * 1024];
  }
  partial[((size_t)b * 8 + sck) * 1024 + d] = (s0 + s1) + (s2 + s3);
}

// ---- vpart[b][dk][c] = sum_{d in chunk} meanX[b][d]*Wv[d][c]; meanX folded ----
__global__ __launch_bounds__(256) void vpartk(const float* __restrict__ partial,
                                              const float* __restrict__ Wv,
                                              float* __restrict__ vpart) {
  const int b = blockIdx.x, cq = blockIdx.y, dk = blockIdx.z;
  const int t = threadIdx.x;
  __shared__ float mx[128];
  if (t < 128) {
    const int d = dk * 128 + t;
    float m = 0;
#pragma unroll
    for (int i = 0; i < 8; ++i) m += partial[((size_t)b * 8 + i) * 1024 + d];
    mx[t] = m * (1.0f / 2048.0f);
  }
  __syncthreads();
  const int c = cq * 256 + t;
  const float* wp = Wv + (size_t)(dk * 128) * 1024 + c;
  float acc = 0;
#pragma unroll 4
  for (int i = 0; i < 128; ++i) acc += mx[i] * wp[(size_t)i * 1024];
  vpart[((size_t)b * 8 + dk) * 1024 + c] = acc;
}

// ---- vmean[b][c] = bv[c] + sum_dk vpart[b][dk][c] ----
__global__ __launch_bounds__(256) void vmeanred(const float* __restrict__ vpart,
                                                const float* __restrict__ bv,
                                                float* __restrict__ vmean) {
  const int b = blockIdx.x;
  const int c = blockIdx.y * 256 + threadIdx.x;
  float acc = bv[c];
#pragma unroll
  for (int i = 0; i < 8; ++i) acc += vpart[((size_t)b * 8 + i) * 1024 + c];
  vmean[b * 1024 + c] = acc;
}

// ---- out rows for masked q: broadcast vmean ----
__global__ __launch_bounds__(256) void bcast(const int* __restrict__ mask,
                                             const float* __restrict__ vmean,
                                             float* __restrict__ out) {
  const int b = blockIdx.y, row = blockIdx.x;
  if (mask[b * 2048 + row] != 0) return;
  const float4 vv = ((const float4*)(vmean + b * 1024))[threadIdx.x];
  ((float4*)(out + ((size_t)b * 2048 + row) * 1024))[threadIdx.x] = vv;
}

// ---- fused weight transpose (z selects Wq/Wk/Wv) ----
__global__ __launch_bounds__(256) void wtrans3(const float* __restrict__ Wq,
                                               const float* __restrict__ Wk,
                                               const float* __restrict__ Wv,
                                               u16* __restrict__ WT) {
  __shared__ float tile[32][33];
  const int z = blockIdx.z;
  const float* W = (z == 0) ? Wq : (z == 1) ? Wk : Wv;
  u16* out = WT + (size_t)z * 1024 * 1024;
  const int tx = threadIdx.x, ty = threadIdx.y;  // 32 x 8
  const int d0 = blockIdx.y * 32, n0 = blockIdx.x * 32;
#pragma unroll
  for (int i = 0; i < 4; ++i)
    tile[ty + 8 * i][tx] = W[(size_t)(d0 + ty + 8 * i) * 1024 + n0 + tx];
  __syncthreads();
#pragma unroll
  for (int i = 0; i < 4; ++i)
    out[(size_t)(n0 + ty + 8 * i) * 1024 + d0 + tx] = f2bf(tile[tx][ty + 8 * i]);
}

// ---- m201-faithful 8-phase 256x256 GEMM core ----
// MODE 0: combined projections (o=0 q, 1 k, 2 v-transposed), batched, early-exit
// MODE 2: scores = qc kc^T /32, bf16 out, exits on bm,bn >= nvpad
// MODE 3: PV, runtime K = nvpad[z], scatter epilogue via idx, rows < nv only

#define BAR __builtin_amdgcn_s_barrier()
#define SB __builtin_amdgcn_sched_barrier(0)
#define LGK0 asm volatile("s_waitcnt lgkmcnt(0)" ::: "memory")
#define VM4 asm volatile("s_waitcnt vmcnt(4)" ::: "memory")
#define VM0 asm volatile("s_waitcnt vmcnt(0)" ::: "memory")

// A-fragment read: full mh-half (4 frag rows x 2 ks) = 8 ds_read_b128
#define RDA4(P0, P1, MH)                                      \
  {                                                           \
    _Pragma("unroll") for (int mf_ = 0; mf_ < 4; ++mf_) {     \
      afr[0][mf_] = ld8(P0, (MH) * 8192 + mf_ * 2048);        \
      afr[1][mf_] = ld8(P1, (MH) * 8192 + mf_ * 2048);        \
    }                                                         \
  }

// B-fragment read: one nh-half (2 frag cols x 2 ks) = 4 ds_read_b128
#define RDB2(DST, P0, P1, NH)                                 \
  {                                                           \
    DST[0][0] = ld8(P0, (NH) * 4096);                         \
    DST[0][1] = ld8(P0, (NH) * 4096 + 2048);                  \
    DST[1][0] = ld8(P1, (NH) * 4096);                         \
    DST[1][1] = ld8(P1, (NH) * 4096 + 2048);                  \
  }

// 16 MFMA: one C-quadrant (mh half x nh half) x K=64
#define MQ16(ACC, NH, BF)                                                \
  __builtin_amdgcn_s_setprio(1);                                         \
  {                                                                      \
    _Pragma("unroll") for (int ks_ = 0; ks_ < 2; ++ks_)                  \
        _Pragma("unroll") for (int mf_ = 0; mf_ < 4; ++mf_)              \
            _Pragma("unroll") for (int nf_ = 0; nf_ < 2; ++nf_)          \
                ACC[mf_][(NH) * 2 + nf_] =                               \
                    __builtin_amdgcn_mfma_f32_16x16x32_bf16(             \
                        afr[ks_][mf_], BF[ks_][nf_],                     \
                        ACC[mf_][(NH) * 2 + nf_], 0, 0, 0);              \
  }                                                                      \
  __builtin_amdgcn_s_setprio(0);

template <int MODE>
__global__ __launch_bounds__(512, 2) void gemm8p(
    const u16* __restrict__ A, const u16* __restrict__ B,
    void* __restrict__ C, void* __restrict__ C1, void* __restrict__ C2,
    const float* __restrict__ b0, const float* __restrict__ b1,
    const float* __restrict__ b2,
    const int* __restrict__ nvpadA, const int* __restrict__ nvA,
    const int* __restrict__ idxA,
    int K, int lda, int ldb, int ldc,
    size_t Az, size_t Bz, size_t Cz) {
  __shared__ __attribute__((aligned(16))) char smem[131072];
  const int tid = threadIdx.x;
  const int lane = tid & 63;
  const int w = tid >> 6;
  const int wr = w >> 2;
  const int wc = w & 3;

  // decode: batch-per-XCD (z = bx & 7)
  const int bx = blockIdx.x;
  const int z = bx & 7;
  int r = bx >> 3;
  int bm, bn, o = 0;
  if constexpr (MODE == 0) { o = r >> 5; r &= 31; bm = r >> 2; bn = r & 3; }
  else if constexpr (MODE == 2) { bm = r >> 3; bn = r & 7; }
  else { bm = r >> 2; bn = r & 3; }

  const int nvp = nvpadA[z];
  if (bm * 256 >= nvp) return;
  if constexpr (MODE == 2) { if (bn * 256 >= nvp) return; }

  const u16* Ap = A;
  const u16* Bp = B;
  if constexpr (MODE == 0) {
    Ap += (size_t)o * (8u * 2048u * 1024u) + (size_t)z * (2048u * 1024u);
    Bp += (size_t)o * (1024u * 1024u);
  } else {
    Ap += (size_t)z * Az;
    Bp += (size_t)z * Bz;
  }
  const int Kz = (MODE == 3) ? nvp : K;
  const int half = Kz >> 7;  // iterations; 2 K-tiles (BK=64) each; Kz % 256 == 0

  // staging addressing: linear LDS dest, inverse-swizzled global source
  const int srow = w * 8 + (lane >> 3);
  const int scol = ((lane & 7) ^ (lane >> 3)) << 3;  // elems
  const u16* Ab0 = Ap + (size_t)(bm * 256 + srow) * lda + scol;
  const u16* Ab1 = Ab0 + (size_t)64 * lda;
  const u16* Ab2 = Ab0 + (size_t)128 * lda;
  const u16* Ab3 = Ab0 + (size_t)192 * lda;
  const u16* Bb0 = Bp + (size_t)(bn * 256 + srow) * ldb + scol;
  const u16* Bb1 = Bb0 + (size_t)64 * ldb;
  const u16* Bb2 = Bb0 + (size_t)128 * ldb;
  const u16* Bb3 = Bb0 + (size_t)192 * ldb;
  char* ldsW = smem + w * 1024;

  // fragment read bases
  const int fr = lane & 15;
  const int fq = lane >> 4;
  const int fx = (fr & 7) << 4;
  const char* pak0 = smem + wr * 16384 + fr * 128 + ((fq * 16) ^ fx);
  const char* pak1 = smem + wr * 16384 + fr * 128 + ((64 + fq * 16) ^ fx);
  const char* pak0b = pak0 + 65536;
  const char* pak1b = pak1 + 65536;
  const char* pbk0 = smem + 32768 + wc * 8192 + fr * 128 + ((fq * 16) ^ fx);
  const char* pbk1 = smem + 32768 + wc * 8192 + fr * 128 + ((64 + fq * 16) ^ fx);
  const char* pbk0b = pbk0 + 65536;
  const char* pbk1b = pbk1 + 65536;

  f32x4 acc0[4][4] = {};
  f32x4 acc1[4][4] = {};
  short8 afr[2][4], bf0[2][2], bf1[2][2];

  // prologue: B(t0), A(t0) first (oldest 8), then B(t1); vmcnt(4) -> t0 landed
  stage16(Bb0, ldsW + 32768); stage16(Bb1, ldsW + 40960);
  stage16(Bb2, ldsW + 49152); stage16(Bb3, ldsW + 57344);
  stage16(Ab0, ldsW + 0);     stage16(Ab1, ldsW + 8192);
  stage16(Ab2, ldsW + 16384); stage16(Ab3, ldsW + 24576);
  stage16(Bb0 + 64, ldsW + 98304);  stage16(Bb1 + 64, ldsW + 106496);
  stage16(Bb2 + 64, ldsW + 114688); stage16(Bb3 + 64, ldsW + 122880);
  VM4;
  BAR;

  int koff = 0;
  // steady loop: branch-free; stages exactly 2/phase.
  // iter i stages: A(2i+1)@p1-2, B(2i+2)@p3-4, A(2i+2)@p5-6, B(2i+3)@p7-8.
  for (int i = 0; i < half - 1; ++i) {
    const int o1 = koff + 64, o2 = koff + 128, o3 = koff + 192;
    // p1 (t0,m0,n0)
    RDA4(pak0, pak1, 0); RDB2(bf0, pbk0, pbk1, 0);
    stage16(Ab0 + o1, ldsW + 65536); stage16(Ab1 + o1, ldsW + 73728);
    SB; BAR; LGK0; MQ16(acc0, 0, bf0); BAR;
    // p2 (t0,m0,n1)
    RDB2(bf1, pbk0, pbk1, 1);
    stage16(Ab2 + o1, ldsW + 81920); stage16(Ab3 + o1, ldsW + 90112);
    SB; BAR; LGK0; MQ16(acc0, 1, bf1); BAR;
    // p3 (t0,m1,n0)
    RDA4(pak0, pak1, 1);
    stage16(Bb0 + o2, ldsW + 32768); stage16(Bb1 + o2, ldsW + 40960);
    SB; BAR; LGK0; MQ16(acc1, 0, bf0); BAR;
    // p4 (t0,m1,n1)
    stage16(Bb2 + o2, ldsW + 49152); stage16(Bb3 + o2, ldsW + 57344);
    SB; BAR; MQ16(acc1, 1, bf1); VM4; BAR;  // t1 (B@prev p7-8, A@p1-2) landed
    // p5 (t1,m0,n0)
    RDA4(pak0b, pak1b, 0); RDB2(bf0, pbk0b, pbk1b, 0);
    stage16(Ab0 + o2, ldsW + 0); stage16(Ab1 + o2, ldsW + 8192);
    SB; BAR; LGK0; MQ16(acc0, 0, bf0); BAR;
    // p6 (t1,m0,n1)
    RDB2(bf1, pbk0b, pbk1b, 1);
    stage16(Ab2 + o2, ldsW + 16384); stage16(Ab3 + o2, ldsW + 24576);
    SB; BAR; LGK0; MQ16(acc0, 1, bf1); BAR;
    // p7 (t1,m1,n0)
    RDA4(pak0b, pak1b, 1);
    stage16(Bb0 + o3, ldsW + 98304); stage16(Bb1 + o3, ldsW + 106496);
    SB; BAR; LGK0; MQ16(acc1, 0, bf0); BAR;
    // p8 (t1,m1,n1)
    stage16(Bb2 + o3, ldsW + 114688); stage16(Bb3 + o3, ldsW + 122880);
    SB; BAR; MQ16(acc1, 1, bf1); VM4; BAR;  // next t0 (B,A@p3-6) landed
    koff += 128;
  }
  // final iteration: stages only A(t1)@p1-2; vmcnt(0) at p4; none at p8.
  {
    const int o1 = koff + 64;
    RDA4(pak0, pak1, 0); RDB2(bf0, pbk0, pbk1, 0);
    stage16(Ab0 + o1, ldsW + 65536); stage16(Ab1 + o1, ldsW + 73728);
    SB; BAR; LGK0; MQ16(acc0, 0, bf0); BAR;
    RDB2(bf1, pbk0, pbk1, 1);
    stage16(Ab2 + o1, ldsW + 81920); stage16(Ab3 + o1, ldsW + 90112);
    SB; BAR; LGK0; MQ16(acc0, 1, bf1); BAR;
    RDA4(pak0, pak1, 1);
    SB; BAR; LGK0; MQ16(acc1, 0, bf0); BAR;
    SB; BAR; MQ16(acc1, 1, bf1); VM0; BAR;  // drain all of t1
    RDA4(pak0b, pak1b, 0); RDB2(bf0, pbk0b, pbk1b, 0);
    SB; BAR; LGK0; MQ16(acc0, 0, bf0); BAR;
    RDB2(bf1, pbk0b, pbk1b, 1);
    SB; BAR; LGK0; MQ16(acc0, 1, bf1); BAR;
    RDA4(pak0b, pak1b, 1);
    SB; BAR; LGK0; MQ16(acc1, 0, bf0); BAR;
    SB; BAR; MQ16(acc1, 1, bf1); BAR;
  }

  // epilogue. D frag layout: col = fr, row = fq*4 + j.
  const int colb = bn * 256 + wc * 64 + fr;
#pragma unroll
  for (int mh = 0; mh < 2; ++mh) {
    f32x4(&ac)[4][4] = mh ? acc1 : acc0;
    const int rowl = bm * 256 + wr * 128 + mh * 64 + fq * 4;  // local row
    if constexpr (MODE == 0) {
      if (o < 2) {
        const float* bp = o ? b1 : b0;
        u16* Cb = (u16*)(o ? C1 : C) + (size_t)z * (2048u * 1024u);
#pragma unroll
        for (int mf = 0; mf < 4; ++mf)
#pragma unroll
          for (int n = 0; n < 4; ++n) {
            const int c = colb + n * 16;
            const float bv = bp[c];
#pragma unroll
            for (int j = 0; j < 4; ++j)
              Cb[(size_t)(rowl + mf * 16 + j) * 1024 + c] =
                  f2bf(ac[mf][n][j] + bv);
          }
      } else {
        u16* Cb = (u16*)C2;  // vcT [8][1024][2048]
#pragma unroll
        for (int mf = 0; mf < 4; ++mf) {
          const int s_ = rowl + mf * 16;
#pragma unroll
          for (int n = 0; n < 4; ++n) {
            const int c = colb + n * 16;
            const float bv = b2[c];
            ushort4 ov;
            ov.x = f2bf(ac[mf][n][0] + bv);
            ov.y = f2bf(ac[mf][n][1] + bv);
            ov.z = f2bf(ac[mf][n][2] + bv);
            ov.w = f2bf(ac[mf][n][3] + bv);
            *(ushort4*)&Cb[((size_t)z * 1024 + c) * 2048 + s_] = ov;
          }
        }
      }
    } else if constexpr (MODE == 2) {
      u16* Cb = (u16*)C + (size_t)z * Cz;
#pragma unroll
      for (int mf = 0; mf < 4; ++mf)
#pragma unroll
        for (int n = 0; n < 4; ++n) {
          const int c = colb + n * 16;
#pragma unroll
          for (int j = 0; j < 4; ++j)
            Cb[(size_t)(rowl + mf * 16 + j) * ldc + c] =
                f2bf(ac[mf][n][j] * 0.03125f);
        }
    } else {  // MODE 3: scatter to d_out via idx, rows < nv only
      const int nv = nvA[z];
      const int* idxp = idxA + z * 2048;
      float* Ob = (float*)C;
#pragma unroll
      for (int mf = 0; mf < 4; ++mf)
#pragma unroll
        for (int j = 0; j < 4; ++j) {
          const int rowc = rowl + mf * 16 + j;
          if (rowc < nv) {
            const int gr = idxp[rowc];
            float* orow = Ob + ((size_t)z * 2048 + gr) * 1024;
#pragma unroll
            for (int n = 0; n < 4; ++n) orow[colb + n * 16] = ac[mf][n][j];
          }
        }
    }
  }
}

// ---- softmax on compacted rows: cols < nv softmaxed, [nv, nvpad) zeroed ----
__global__ __launch_bounds__(256) void softmaxc(u16* __restrict__ scores,
                                                const int* __restrict__ nvA,
                                                const int* __restrict__ nvpadA) {
  const int b = blockIdx.y, row = blockIdx.x;
  const int nv = nvA[b];
  if (row >= nv) return;
  const int nvp = nvpadA[b];
  const int t = threadIdx.x, lane = t & 63, w = t >> 6;
  u16* sc = scores + ((size_t)b * 2048 + row) * 2048;
  const int c0 = t * 8;
  float v[8];
  if (c0 < nvp) {
    const ushort4 h0 = *(const ushort4*)&sc[c0];
    const ushort4 h1 = *(const ushort4*)&sc[c0 + 4];
    v[0] = bf2f(h0.x); v[1] = bf2f(h0.y); v[2] = bf2f(h0.z); v[3] = bf2f(h0.w);
    v[4] = bf2f(h1.x); v[5] = bf2f(h1.y); v[6] = bf2f(h1.z); v[7] = bf2f(h1.w);
  } else {
#pragma unroll
    for (int i = 0; i < 8; ++i) v[i] = 0.f;
  }
  float lmax = -3.0e38f;
#pragma unroll
  for (int i = 0; i < 8; ++i)
    if (c0 + i < nv) lmax = fmaxf(lmax, v[i]);
#pragma unroll
  for (int off = 32; off >= 1; off >>= 1) lmax = fmaxf(lmax, __shfl_xor(lmax, off));
  __shared__ float red[8];
  if (lane == 0) red[w] = lmax;
  __syncthreads();
  const float bmax = fmaxf(fmaxf(red[0], red[1]), fmaxf(red[2], red[3]));
  float e[8];
  float lsum = 0.f;
#pragma unroll
  for (int i = 0; i < 8; ++i) {
    e[i] = (c0 + i < nv) ? __expf(v[i] - bmax) : 0.f;
    lsum += e[i];
  }
#pragma unroll
  for (int off = 32; off >= 1; off >>= 1) lsum += __shfl_xor(lsum, off);
  if (lane == 0) red[4 + w] = lsum;
  __syncthreads();
  const float inv = 1.0f / ((red[4] + red[5]) + (red[6] + red[7]));
  if (c0 < nvp) {
    ushort4 o0, o1;
    o0.x = f2bf(e[0] * inv); o0.y = f2bf(e[1] * inv);
    o0.z = f2bf(e[2] * inv); o0.w = f2bf(e[3] * inv);
    o1.x = f2bf(e[4] * inv); o1.y = f2bf(e[5] * inv);
    o1.z = f2bf(e[6] * inv); o1.w = f2bf(e[7] * inv);
    *(ushort4*)&sc[c0] = o0;
    *(ushort4*)&sc[c0 + 4] = o1;
  }
}

extern "C" void kernel_launch(void* const* d_in, const int* in_sizes, int n_in,
                              void* d_out, int out_size, void* d_ws, size_t ws_size,
                              hipStream_t stream) {
  const float* in_q = (const float*)d_in[0];
  const float* in_k = (const float*)d_in[1];
  const float* in_v = (const float*)d_in[2];
  const int* mask = (const int*)d_in[3];
  const float* Wq = (const float*)d_in[4];
  const float* bq = (const float*)d_in[5];
  const float* Wk = (const float*)d_in[6];
  const float* bk = (const float*)d_in[7];
  const float* Wv = (const float*)d_in[8];
  const float* bv = (const float*)d_in[9];

  char* ws = (char*)d_ws;
  const size_t SZ = (size_t)16384 * 1024 * 2;  // 32M bytes
  u16* qc = (u16*)(ws);
  u16* kc = (u16*)(ws + SZ);
  u16* vcT = (u16*)(ws + 2 * SZ);
  u16* Xc = (u16*)(ws + 3 * SZ);        // Xqc, Xkc, Xvc (32M each)
  u16* Xqc = Xc;
  u16* Xkc = Xc + (size_t)8 * 2048 * 1024;
  u16* Xvc = Xkc + (size_t)8 * 2048 * 1024;
  u16* scores = (u16*)(ws + 3 * SZ);    // overlays Xc after projections
  u16* WT = (u16*)(ws + 6 * SZ);        // WqT, WkT, WvT contiguous
  char* misc = ws + 6 * SZ + 6 * 1024 * 1024;
  int* idxA = (int*)misc;               // [8][2048] = 64KB
  int* nvA = idxA + 8 * 2048;
  int* nvpadA = nvA + 8;
  float* partial = (float*)(misc + 128 * 1024);  // [8][8][1024] = 256KB
  float* vmean = (float*)(misc + 384 * 1024);    // [8][1024] = 32KB
  float* vpart = (float*)(misc + 448 * 1024);    // [8][8][1024] = 256KB

  // 1) mask scan -> idx, nv, nvpad
  maskscan<<<8, 256, 0, stream>>>(mask, idxA, nvA, nvpadA);

  // 2) fused gather+convert (q,k,v in one dispatch); vmean path
  compact3<<<dim3(2048, 8, 3), 256, 0, stream>>>(in_q, in_k, in_v, idxA, nvA,
                                                 Xqc, Xkc, Xvc);
  colpart<<<dim3(8, 4, 8), 256, 0, stream>>>(in_v, partial);
  vpartk<<<dim3(8, 4, 8), 256, 0, stream>>>(partial, Wv, vpart);
  vmeanred<<<dim3(8, 4), 256, 0, stream>>>(vpart, bv, vmean);

  // 3) fused weight transposes (one dispatch)
  wtrans3<<<dim3(32, 32, 3), dim3(32, 8), 0, stream>>>(Wq, Wk, Wv, WT);

  // 4) all three projections, one dispatch: grid 8z * (3o * 8bm * 4bn) = 768
  gemm8p<0><<<768, 512, 0, stream>>>(
      Xqc, WT, qc, kc, vcT, bq, bk, bv, nvpadA, nvA, idxA,
      1024, 1024, 1024, 1024, 0, 0, 0);

  // 5) scores[b] = qc kc^T / 32 : grid 8z * (8bm * 8bn) = 512
  gemm8p<2><<<512, 512, 0, stream>>>(
      qc, kc, scores, nullptr, nullptr, nullptr, nullptr, nullptr,
      nvpadA, nvA, idxA, 1024, 1024, 1024, 2048,
      (size_t)2048 * 1024, (size_t)2048 * 1024, (size_t)2048 * 2048);

  // 6) compacted softmax (in place)
  softmaxc<<<dim3(2048, 8), 256, 0, stream>>>(scores, nvA, nvpadA);

  // 7) PV with scatter: grid 8z * (8bm * 4bn) = 256; K = nvpad[z]
  gemm8p<3><<<256, 512, 0, stream>>>(
      scores, vcT, d_out, nullptr, nullptr, nullptr, nullptr, nullptr,
      nvpadA, nvA, idxA, 0, 2048, 2048, 1024,
      (size_t)2048 * 2048, (size_t)1024 * 2048, 0);

  // 8) masked q-rows: out = vmean
  bcast<<<dim3(2048, 8), 256, 0, stream>>>(mask, vmean, (float*)d_out);
}

// Round 13
// 255.684 us; speedup vs baseline: 1.1050x; 1.1050x over previous
//
#include <hip/hip_runtime.h>
#include <stdint.h>

// SelfAttentionV3 with mask-compaction. B=8, S=2048, D=1024.
// R13: scores & PV moved to the R1-proven 128x128/BK32/4-wave GEMM core
// (8 blocks/CU co-resident, grids ~650 active blocks fill the chip) with
// 128-aligned padding (nvpad128) — cuts the ~26% nvpad^2 overcompute of
// 256-aligned tiles. projAll stays on the 256^2 8-phase core (744 TF).

typedef unsigned short u16;
typedef __attribute__((ext_vector_type(8))) short short8;
typedef __attribute__((ext_vector_type(4))) float f32x4;

__device__ __forceinline__ u16 f2bf(float x) {
  unsigned u = __float_as_uint(x);
  return (u16)((u + 0x7FFFu + ((u >> 16) & 1u)) >> 16);  // RNE
}
__device__ __forceinline__ float bf2f(u16 h) {
  return __uint_as_float(((unsigned)h) << 16);
}

__device__ __forceinline__ void stage16(const void* g, void* l) {
  const __attribute__((address_space(1))) uint32_t* gp =
      (const __attribute__((address_space(1))) uint32_t*)(uintptr_t)g;
  __attribute__((address_space(3))) uint32_t* lp =
      (__attribute__((address_space(3))) uint32_t*)(uintptr_t)l;
  __builtin_amdgcn_global_load_lds(gp, lp, 16, 0, 0);
}

__device__ __forceinline__ short8 ld8(const char* p, int off) {
  return *(const short8*)(p + off);
}

// ---- mask prefix-scan: per batch -> idx list, nv, nvpad256, nvpad128 ----
__global__ __launch_bounds__(256) void maskscan(const int* __restrict__ mask,
                                                int* __restrict__ idxA,
                                                int* __restrict__ nvA,
                                                int* __restrict__ nvpadA,
                                                int* __restrict__ nvp128A) {
  const int b = blockIdx.x;
  const int t = threadIdx.x, lane = t & 63, w = t >> 6;
  const int* m = mask + b * 2048;
  int v[8], loc = 0;
#pragma unroll
  for (int i = 0; i < 8; ++i) { v[i] = m[t * 8 + i]; loc += v[i]; }
  int sc = loc;  // inclusive scan over 64 lanes
  for (int off = 1; off < 64; off <<= 1) {
    int n = __shfl_up(sc, off);
    if (lane >= off) sc += n;
  }
  __shared__ int wsum[4];
  if (lane == 63) wsum[w] = sc;
  __syncthreads();
  int woff = 0;
  for (int i = 0; i < w; ++i) woff += wsum[i];
  int pos = woff + sc - loc;  // exclusive prefix
#pragma unroll
  for (int i = 0; i < 8; ++i)
    if (v[i]) idxA[b * 2048 + (pos++)] = t * 8 + i;
  if (t == 255) {
    const int nv = woff + sc;
    nvA[b] = nv;
    nvpadA[b] = (nv + 255) & ~255;
    nvp128A[b] = (nv + 127) & ~127;
  }
}

// ---- fused gather+convert for q,k,v (z selects input) ----
__global__ __launch_bounds__(256) void compact3(const float* __restrict__ Xq,
                                                const float* __restrict__ Xk,
                                                const float* __restrict__ Xv,
                                                const int* __restrict__ idxA,
                                                const int* __restrict__ nvA,
                                                u16* __restrict__ Oq,
                                                u16* __restrict__ Ok,
                                                u16* __restrict__ Ov) {
  const int b = blockIdx.y, j = blockIdx.x, z = blockIdx.z;
  if (j >= nvA[b]) return;
  const float* X = (z == 0) ? Xq : (z == 1) ? Xk : Xv;
  u16* out = (z == 0) ? Oq : (z == 1) ? Ok : Ov;
  const int src = idxA[b * 2048 + j];
  const float4* s = (const float4*)(X + ((size_t)b * 2048 + src) * 1024);
  ushort4* d = (ushort4*)(out + ((size_t)b * 2048 + j) * 1024);
  const float4 f = s[threadIdx.x];
  ushort4 o;
  o.x = f2bf(f.x); o.y = f2bf(f.y); o.z = f2bf(f.z); o.w = f2bf(f.w);
  d[threadIdx.x] = o;
}

// ---- column partial sums of Xv (all 2048 rows) ----
__global__ __launch_bounds__(256) void colpart(const float* __restrict__ X,
                                               float* __restrict__ partial) {
  const int b = blockIdx.x, dq = blockIdx.y, sck = blockIdx.z;
  const int d = dq * 256 + threadIdx.x;
  const float* p = X + ((size_t)b * 2048 + sck * 256) * 1024 + d;
  float s0 = 0, s1 = 0, s2 = 0, s3 = 0;
  for (int r = 0; r < 256; r += 4) {
    s0 += p[(size_t)(r + 0) * 1024];
    s1 += p[(size_t)(r + 1) * 1024];
    s2 += p[(size_t)(r + 2) * 1024];
    s3 += p[(size_t)(r + 3) * 1024];
  }
  partial[((size_t)b * 8 + sck) * 1024 + d] = (s0 + s1) + (s2 + s3);
}

// ---- vpart[b][dk][c] = sum_{d in chunk} meanX[b][d]*Wv[d][c]; meanX folded ----
__global__ __launch_bounds__(256) void vpartk(const float* __restrict__ partial,
                                              const float* __restrict__ Wv,
                                              float* __restrict__ vpart) {
  const int b = blockIdx.x, cq = blockIdx.y, dk = blockIdx.z;
  const int t = threadIdx.x;
  __shared__ float mx[128];
  if (t < 128) {
    const int d = dk * 128 + t;
    float m = 0;
#pragma unroll
    for (int i = 0; i < 8; ++i) m += partial[((size_t)b * 8 + i) * 1024 + d];
    mx[t] = m * (1.0f / 2048.0f);
  }
  __syncthreads();
  const int c = cq * 256 + t;
  const float* wp = Wv + (size_t)(dk * 128) * 1024 + c;
  float acc = 0;
#pragma unroll 4
  for (int i = 0; i < 128; ++i) acc += mx[i] * wp[(size_t)i * 1024];
  vpart[((size_t)b * 8 + dk) * 1024 + c] = acc;
}

// ---- vmean[b][c] = bv[c] + sum_dk vpart[b][dk][c] ----
__global__ __launch_bounds__(256) void vmeanred(const float* __restrict__ vpart,
                                                const float* __restrict__ bv,
                                                float* __restrict__ vmean) {
  const int b = blockIdx.x;
  const int c = blockIdx.y * 256 + threadIdx.x;
  float acc = bv[c];
#pragma unroll
  for (int i = 0; i < 8; ++i) acc += vpart[((size_t)b * 8 + i) * 1024 + c];
  vmean[b * 1024 + c] = acc;
}

// ---- out rows for masked q: broadcast vmean ----
__global__ __launch_bounds__(256) void bcast(const int* __restrict__ mask,
                                             const float* __restrict__ vmean,
                                             float* __restrict__ out) {
  const int b = blockIdx.y, row = blockIdx.x;
  if (mask[b * 2048 + row] != 0) return;
  const float4 vv = ((const float4*)(vmean + b * 1024))[threadIdx.x];
  ((float4*)(out + ((size_t)b * 2048 + row) * 1024))[threadIdx.x] = vv;
}

// ---- fused weight transpose (z selects Wq/Wk/Wv) ----
__global__ __launch_bounds__(256) void wtrans3(const float* __restrict__ Wq,
                                               const float* __restrict__ Wk,
                                               const float* __restrict__ Wv,
                                               u16* __restrict__ WT) {
  __shared__ float tile[32][33];
  const int z = blockIdx.z;
  const float* W = (z == 0) ? Wq : (z == 1) ? Wk : Wv;
  u16* out = WT + (size_t)z * 1024 * 1024;
  const int tx = threadIdx.x, ty = threadIdx.y;  // 32 x 8
  const int d0 = blockIdx.y * 32, n0 = blockIdx.x * 32;
#pragma unroll
  for (int i = 0; i < 4; ++i)
    tile[ty + 8 * i][tx] = W[(size_t)(d0 + ty + 8 * i) * 1024 + n0 + tx];
  __syncthreads();
#pragma unroll
  for (int i = 0; i < 4; ++i)
    out[(size_t)(n0 + ty + 8 * i) * 1024 + d0 + tx] = f2bf(tile[tx][ty + 8 * i]);
}

// ================= 256x256 8-phase core: projections only =================
#define BAR __builtin_amdgcn_s_barrier()
#define SB __builtin_amdgcn_sched_barrier(0)
#define LGK0 asm volatile("s_waitcnt lgkmcnt(0)" ::: "memory")
#define VM4 asm volatile("s_waitcnt vmcnt(4)" ::: "memory")
#define VM0 asm volatile("s_waitcnt vmcnt(0)" ::: "memory")

#define RDA4(P0, P1, MH)                                      \
  {                                                           \
    _Pragma("unroll") for (int mf_ = 0; mf_ < 4; ++mf_) {     \
      afr[0][mf_] = ld8(P0, (MH) * 8192 + mf_ * 2048);        \
      afr[1][mf_] = ld8(P1, (MH) * 8192 + mf_ * 2048);        \
    }                                                         \
  }

#define RDB2(DST, P0, P1, NH)                                 \
  {                                                           \
    DST[0][0] = ld8(P0, (NH) * 4096);                         \
    DST[0][1] = ld8(P0, (NH) * 4096 + 2048);                  \
    DST[1][0] = ld8(P1, (NH) * 4096);                         \
    DST[1][1] = ld8(P1, (NH) * 4096 + 2048);                  \
  }

#define MQ16(ACC, NH, BF)                                                \
  __builtin_amdgcn_s_setprio(1);                                         \
  {                                                                      \
    _Pragma("unroll") for (int ks_ = 0; ks_ < 2; ++ks_)                  \
        _Pragma("unroll") for (int mf_ = 0; mf_ < 4; ++mf_)              \
            _Pragma("unroll") for (int nf_ = 0; nf_ < 2; ++nf_)          \
                ACC[mf_][(NH) * 2 + nf_] =                               \
                    __builtin_amdgcn_mfma_f32_16x16x32_bf16(             \
                        afr[ks_][mf_], BF[ks_][nf_],                     \
                        ACC[mf_][(NH) * 2 + nf_], 0, 0, 0);              \
  }                                                                      \
  __builtin_amdgcn_s_setprio(0);

// MODE 0 only: combined projections (o=0 q, 1 k, 2 v-transposed)
template <int MODE>
__global__ __launch_bounds__(512, 2) void gemm8p(
    const u16* __restrict__ A, const u16* __restrict__ B,
    void* __restrict__ C, void* __restrict__ C1, void* __restrict__ C2,
    const float* __restrict__ b0, const float* __restrict__ b1,
    const float* __restrict__ b2,
    const int* __restrict__ nvpadA,
    int K, int lda, int ldb, int ldc) {
  __shared__ __attribute__((aligned(16))) char smem[131072];
  const int tid = threadIdx.x;
  const int lane = tid & 63;
  const int w = tid >> 6;
  const int wr = w >> 2;
  const int wc = w & 3;

  const int bx = blockIdx.x;
  const int z = bx & 7;
  int r = bx >> 3;
  const int o = r >> 5; r &= 31;
  const int bm = r >> 2, bn = r & 3;

  const int nvp = nvpadA[z];
  if (bm * 256 >= nvp) return;

  const u16* Ap = A + (size_t)o * (8u * 2048u * 1024u) + (size_t)z * (2048u * 1024u);
  const u16* Bp = B + (size_t)o * (1024u * 1024u);
  const int half = K >> 7;

  const int srow = w * 8 + (lane >> 3);
  const int scol = ((lane & 7) ^ (lane >> 3)) << 3;  // elems
  const u16* Ab0 = Ap + (size_t)(bm * 256 + srow) * lda + scol;
  const u16* Ab1 = Ab0 + (size_t)64 * lda;
  const u16* Ab2 = Ab0 + (size_t)128 * lda;
  const u16* Ab3 = Ab0 + (size_t)192 * lda;
  const u16* Bb0 = Bp + (size_t)(bn * 256 + srow) * ldb + scol;
  const u16* Bb1 = Bb0 + (size_t)64 * ldb;
  const u16* Bb2 = Bb0 + (size_t)128 * ldb;
  const u16* Bb3 = Bb0 + (size_t)192 * ldb;
  char* ldsW = smem + w * 1024;

  const int fr = lane & 15;
  const int fq = lane >> 4;
  const int fx = (fr & 7) << 4;
  const char* pak0 = smem + wr * 16384 + fr * 128 + ((fq * 16) ^ fx);
  const char* pak1 = smem + wr * 16384 + fr * 128 + ((64 + fq * 16) ^ fx);
  const char* pak0b = pak0 + 65536;
  const char* pak1b = pak1 + 65536;
  const char* pbk0 = smem + 32768 + wc * 8192 + fr * 128 + ((fq * 16) ^ fx);
  const char* pbk1 = smem + 32768 + wc * 8192 + fr * 128 + ((64 + fq * 16) ^ fx);
  const char* pbk0b = pbk0 + 65536;
  const char* pbk1b = pbk1 + 65536;

  f32x4 acc0[4][4] = {};
  f32x4 acc1[4][4] = {};
  short8 afr[2][4], bf0[2][2], bf1[2][2];

  stage16(Bb0, ldsW + 32768); stage16(Bb1, ldsW + 40960);
  stage16(Bb2, ldsW + 49152); stage16(Bb3, ldsW + 57344);
  stage16(Ab0, ldsW + 0);     stage16(Ab1, ldsW + 8192);
  stage16(Ab2, ldsW + 16384); stage16(Ab3, ldsW + 24576);
  stage16(Bb0 + 64, ldsW + 98304);  stage16(Bb1 + 64, ldsW + 106496);
  stage16(Bb2 + 64, ldsW + 114688); stage16(Bb3 + 64, ldsW + 122880);
  VM4;
  BAR;

  int koff = 0;
  for (int i = 0; i < half - 1; ++i) {
    const int o1 = koff + 64, o2 = koff + 128, o3 = koff + 192;
    RDA4(pak0, pak1, 0); RDB2(bf0, pbk0, pbk1, 0);
    stage16(Ab0 + o1, ldsW + 65536); stage16(Ab1 + o1, ldsW + 73728);
    SB; BAR; LGK0; MQ16(acc0, 0, bf0); BAR;
    RDB2(bf1, pbk0, pbk1, 1);
    stage16(Ab2 + o1, ldsW + 81920); stage16(Ab3 + o1, ldsW + 90112);
    SB; BAR; LGK0; MQ16(acc0, 1, bf1); BAR;
    RDA4(pak0, pak1, 1);
    stage16(Bb0 + o2, ldsW + 32768); stage16(Bb1 + o2, ldsW + 40960);
    SB; BAR; LGK0; MQ16(acc1, 0, bf0); BAR;
    stage16(Bb2 + o2, ldsW + 49152); stage16(Bb3 + o2, ldsW + 57344);
    SB; BAR; MQ16(acc1, 1, bf1); VM4; BAR;
    RDA4(pak0b, pak1b, 0); RDB2(bf0, pbk0b, pbk1b, 0);
    stage16(Ab0 + o2, ldsW + 0); stage16(Ab1 + o2, ldsW + 8192);
    SB; BAR; LGK0; MQ16(acc0, 0, bf0); BAR;
    RDB2(bf1, pbk0b, pbk1b, 1);
    stage16(Ab2 + o2, ldsW + 16384); stage16(Ab3 + o2, ldsW + 24576);
    SB; BAR; LGK0; MQ16(acc0, 1, bf1); BAR;
    RDA4(pak0b, pak1b, 1);
    stage16(Bb0 + o3, ldsW + 98304); stage16(Bb1 + o3, ldsW + 106496);
    SB; BAR; LGK0; MQ16(acc1, 0, bf0); BAR;
    stage16(Bb2 + o3, ldsW + 114688); stage16(Bb3 + o3, ldsW + 122880);
    SB; BAR; MQ16(acc1, 1, bf1); VM4; BAR;
    koff += 128;
  }
  {
    const int o1 = koff + 64;
    RDA4(pak0, pak1, 0); RDB2(bf0, pbk0, pbk1, 0);
    stage16(Ab0 + o1, ldsW + 65536); stage16(Ab1 + o1, ldsW + 73728);
    SB; BAR; LGK0; MQ16(acc0, 0, bf0); BAR;
    RDB2(bf1, pbk0, pbk1, 1);
    stage16(Ab2 + o1, ldsW + 81920); stage16(Ab3 + o1, ldsW + 90112);
    SB; BAR; LGK0; MQ16(acc0, 1, bf1); BAR;
    RDA4(pak0, pak1, 1);
    SB; BAR; LGK0; MQ16(acc1, 0, bf0); BAR;
    SB; BAR; MQ16(acc1, 1, bf1); VM0; BAR;
    RDA4(pak0b, pak1b, 0); RDB2(bf0, pbk0b, pbk1b, 0);
    SB; BAR; LGK0; MQ16(acc0, 0, bf0); BAR;
    RDB2(bf1, pbk0b, pbk1b, 1);
    SB; BAR; LGK0; MQ16(acc0, 1, bf1); BAR;
    RDA4(pak0b, pak1b, 1);
    SB; BAR; LGK0; MQ16(acc1, 0, bf0); BAR;
    SB; BAR; MQ16(acc1, 1, bf1); BAR;
  }

  const int colb = bn * 256 + wc * 64 + fr;
#pragma unroll
  for (int mh = 0; mh < 2; ++mh) {
    f32x4(&ac)[4][4] = mh ? acc1 : acc0;
    const int rowl = bm * 256 + wr * 128 + mh * 64 + fq * 4;
    if (o < 2) {
      const float* bp = o ? b1 : b0;
      u16* Cb = (u16*)(o ? C1 : C) + (size_t)z * (2048u * 1024u);
#pragma unroll
      for (int mf = 0; mf < 4; ++mf)
#pragma unroll
        for (int n = 0; n < 4; ++n) {
          const int c = colb + n * 16;
          const float bv = bp[c];
#pragma unroll
          for (int j = 0; j < 4; ++j)
            Cb[(size_t)(rowl + mf * 16 + j) * ldc + c] = f2bf(ac[mf][n][j] + bv);
        }
    } else {
      u16* Cb = (u16*)C2;  // vcT [8][1024][2048]
#pragma unroll
      for (int mf = 0; mf < 4; ++mf) {
        const int s_ = rowl + mf * 16;
#pragma unroll
        for (int n = 0; n < 4; ++n) {
          const int c = colb + n * 16;
          const float bv = b2[c];
          ushort4 ov;
          ov.x = f2bf(ac[mf][n][0] + bv);
          ov.y = f2bf(ac[mf][n][1] + bv);
          ov.z = f2bf(ac[mf][n][2] + bv);
          ov.w = f2bf(ac[mf][n][3] + bv);
          *(ushort4*)&Cb[((size_t)z * 1024 + c) * 2048 + s_] = ov;
        }
      }
    }
  }
}

// ================= 128x128/BK32 4-wave core (R1-proven): scores & PV ========
// MODE 2: scores = qc kc^T /32 (bf16 out). MODE 3: PV -> d_out scatter (fp32).
// 8 blocks/CU co-resident; K runtime (PV: nvp128[z]).
template <int MODE>
__global__ __launch_bounds__(256, 2) void gemm128(
    const u16* __restrict__ A, const u16* __restrict__ B, void* __restrict__ C,
    const int* __restrict__ nvp128A, const int* __restrict__ nvA,
    const int* __restrict__ idxA,
    int K, int lda, int ldb, int ldc,
    size_t Az, size_t Bz, size_t Cz) {
  __shared__ __attribute__((aligned(16))) u16 lsA[128 * 32];
  __shared__ __attribute__((aligned(16))) u16 lsB[128 * 32];
  const int tid = threadIdx.x;
  const int lane = tid & 63;
  const int w = tid >> 6;      // 0..3
  const int wr = w >> 1, wc = w & 1;

  const int bx = blockIdx.x;
  const int z = bx & 7;
  const int r = bx >> 3;
  int bm, bn;
  if constexpr (MODE == 2) { bm = r >> 4; bn = r & 15; }   // 16 x 16
  else                     { bm = r >> 3; bn = r & 7; }    // 16 x 8

  const int nvp = nvp128A[z];
  if (bm * 128 >= nvp) return;
  if constexpr (MODE == 2) { if (bn * 128 >= nvp) return; }
  const int Kz = (MODE == 3) ? nvp : K;

  const u16* Ap = A + (size_t)z * Az;
  const u16* Bp = B + (size_t)z * Bz;

  // staging: wave w stages rows [w*32, w*32+32); one stage16 = 16 rows.
  const int srow = lane >> 2;
  const int scol = (lane & 3) * 8;
  const u16* Ag0 = Ap + (size_t)(bm * 128 + w * 32 + srow) * lda + scol;
  const u16* Ag1 = Ag0 + (size_t)16 * lda;
  const u16* Bg0 = Bp + (size_t)(bn * 128 + w * 32 + srow) * ldb + scol;
  const u16* Bg1 = Bg0 + (size_t)16 * ldb;
  u16* lA0 = &lsA[(w * 32) * 32];
  u16* lA1 = &lsA[(w * 32 + 16) * 32];
  u16* lB0 = &lsB[(w * 32) * 32];
  u16* lB1 = &lsB[(w * 32 + 16) * 32];

  const int arow = wr * 64 + (lane & 15);
  const int brow = wc * 64 + (lane & 15);
  const int ko = (lane >> 4) * 8;

  f32x4 acc[4][4] = {};

  for (int k0 = 0; k0 < Kz; k0 += 32) {
    stage16(Ag0 + k0, lA0);
    stage16(Ag1 + k0, lA1);
    stage16(Bg0 + k0, lB0);
    stage16(Bg1 + k0, lB1);
    __syncthreads();
    short8 af[4], bfr[4];
#pragma unroll
    for (int m = 0; m < 4; ++m)
      af[m] = *(const short8*)&lsA[(arow + m * 16) * 32 + ko];
#pragma unroll
    for (int n = 0; n < 4; ++n)
      bfr[n] = *(const short8*)&lsB[(brow + n * 16) * 32 + ko];
#pragma unroll
    for (int m = 0; m < 4; ++m)
#pragma unroll
      for (int n = 0; n < 4; ++n)
        acc[m][n] =
            __builtin_amdgcn_mfma_f32_16x16x32_bf16(af[m], bfr[n], acc[m][n], 0, 0, 0);
    __syncthreads();
  }

  // D layout: col = lane&15 (+n*16), row = (lane>>4)*4 + j (+m*16)
  const int col0 = bn * 128 + wc * 64 + (lane & 15);
  const int row0 = bm * 128 + wr * 64 + ((lane >> 4) << 2);

  if constexpr (MODE == 2) {
    u16* Cb = (u16*)C + (size_t)z * Cz;
#pragma unroll
    for (int m = 0; m < 4; ++m)
#pragma unroll
      for (int n = 0; n < 4; ++n) {
        const int c = col0 + n * 16;
#pragma unroll
        for (int j = 0; j < 4; ++j)
          Cb[(size_t)(row0 + m * 16 + j) * ldc + c] =
              f2bf(acc[m][n][j] * 0.03125f);
      }
  } else {  // MODE 3: scatter rows < nv via idx
    const int nv = nvA[z];
    const int* idxp = idxA + z * 2048;
    float* Ob = (float*)C;
#pragma unroll
    for (int m = 0; m < 4; ++m)
#pragma unroll
      for (int j = 0; j < 4; ++j) {
        const int rowc = row0 + m * 16 + j;
        if (rowc < nv) {
          const int gr = idxp[rowc];
          float* orow = Ob + ((size_t)z * 2048 + gr) * 1024;
#pragma unroll
          for (int n = 0; n < 4; ++n) orow[col0 + n * 16] = acc[m][n][j];
        }
      }
  }
}

// ---- softmax on compacted rows: cols < nv softmaxed, [nv, nvp128) zeroed ----
__global__ __launch_bounds__(256) void softmaxc(u16* __restrict__ scores,
                                                const int* __restrict__ nvA,
                                                const int* __restrict__ nvp128A) {
  const int b = blockIdx.y, row = blockIdx.x;
  const int nv = nvA[b];
  if (row >= nv) return;
  const int nvp = nvp128A[b];
  const int t = threadIdx.x, lane = t & 63, w = t >> 6;
  u16* sc = scores + ((size_t)b * 2048 + row) * 2048;
  const int c0 = t * 8;
  float v[8];
  if (c0 < nvp) {
    const ushort4 h0 = *(const ushort4*)&sc[c0];
    const ushort4 h1 = *(const ushort4*)&sc[c0 + 4];
    v[0] = bf2f(h0.x); v[1] = bf2f(h0.y); v[2] = bf2f(h0.z); v[3] = bf2f(h0.w);
    v[4] = bf2f(h1.x); v[5] = bf2f(h1.y); v[6] = bf2f(h1.z); v[7] = bf2f(h1.w);
  } else {
#pragma unroll
    for (int i = 0; i < 8; ++i) v[i] = 0.f;
  }
  float lmax = -3.0e38f;
#pragma unroll
  for (int i = 0; i < 8; ++i)
    if (c0 + i < nv) lmax = fmaxf(lmax, v[i]);
#pragma unroll
  for (int off = 32; off >= 1; off >>= 1) lmax = fmaxf(lmax, __shfl_xor(lmax, off));
  __shared__ float red[8];
  if (lane == 0) red[w] = lmax;
  __syncthreads();
  const float bmax = fmaxf(fmaxf(red[0], red[1]), fmaxf(red[2], red[3]));
  float e[8];
  float lsum = 0.f;
#pragma unroll
  for (int i = 0; i < 8; ++i) {
    e[i] = (c0 + i < nv) ? __expf(v[i] - bmax) : 0.f;
    lsum += e[i];
  }
#pragma unroll
  for (int off = 32; off >= 1; off >>= 1) lsum += __shfl_xor(lsum, off);
  if (lane == 0) red[4 + w] = lsum;
  __syncthreads();
  const float inv = 1.0f / ((red[4] + red[5]) + (red[6] + red[7]));
  if (c0 < nvp) {
    ushort4 o0, o1;
    o0.x = f2bf(e[0] * inv); o0.y = f2bf(e[1] * inv);
    o0.z = f2bf(e[2] * inv); o0.w = f2bf(e[3] * inv);
    o1.x = f2bf(e[4] * inv); o1.y = f2bf(e[5] * inv);
    o1.z = f2bf(e[6] * inv); o1.w = f2bf(e[7] * inv);
    *(ushort4*)&sc[c0] = o0;
    *(ushort4*)&sc[c0 + 4] = o1;
  }
}

extern "C" void kernel_launch(void* const* d_in, const int* in_sizes, int n_in,
                              void* d_out, int out_size, void* d_ws, size_t ws_size,
                              hipStream_t stream) {
  const float* in_q = (const float*)d_in[0];
  const float* in_k = (const float*)d_in[1];
  const float* in_v = (const float*)d_in[2];
  const int* mask = (const int*)d_in[3];
  const float* Wq = (const float*)d_in[4];
  const float* bq = (const float*)d_in[5];
  const float* Wk = (const float*)d_in[6];
  const float* bk = (const float*)d_in[7];
  const float* Wv = (const float*)d_in[8];
  const float* bv = (const float*)d_in[9];

  char* ws = (char*)d_ws;
  const size_t SZ = (size_t)16384 * 1024 * 2;  // 32M bytes
  u16* qc = (u16*)(ws);
  u16* kc = (u16*)(ws + SZ);
  u16* vcT = (u16*)(ws + 2 * SZ);
  u16* Xc = (u16*)(ws + 3 * SZ);        // Xqc, Xkc, Xvc (32M each)
  u16* Xqc = Xc;
  u16* Xkc = Xc + (size_t)8 * 2048 * 1024;
  u16* Xvc = Xkc + (size_t)8 * 2048 * 1024;
  u16* scores = (u16*)(ws + 3 * SZ);    // overlays Xc after projections
  u16* WT = (u16*)(ws + 6 * SZ);        // WqT, WkT, WvT contiguous
  char* misc = ws + 6 * SZ + 6 * 1024 * 1024;
  int* idxA = (int*)misc;               // [8][2048] = 64KB
  int* nvA = idxA + 8 * 2048;
  int* nvpadA = nvA + 8;
  int* nvp128A = nvpadA + 8;
  float* partial = (float*)(misc + 128 * 1024);  // [8][8][1024] = 256KB
  float* vmean = (float*)(misc + 384 * 1024);    // [8][1024] = 32KB
  float* vpart = (float*)(misc + 448 * 1024);    // [8][8][1024] = 256KB

  // 1) mask scan -> idx, nv, nvpad256, nvpad128
  maskscan<<<8, 256, 0, stream>>>(mask, idxA, nvA, nvpadA, nvp128A);

  // 2) fused gather+convert; vmean path
  compact3<<<dim3(2048, 8, 3), 256, 0, stream>>>(in_q, in_k, in_v, idxA, nvA,
                                                 Xqc, Xkc, Xvc);
  colpart<<<dim3(8, 4, 8), 256, 0, stream>>>(in_v, partial);
  vpartk<<<dim3(8, 4, 8), 256, 0, stream>>>(partial, Wv, vpart);
  vmeanred<<<dim3(8, 4), 256, 0, stream>>>(vpart, bv, vmean);

  // 3) fused weight transposes
  wtrans3<<<dim3(32, 32, 3), dim3(32, 8), 0, stream>>>(Wq, Wk, Wv, WT);

  // 4) all three projections (256^2 core): 8z * (3o * 8bm * 4bn) = 768
  gemm8p<0><<<768, 512, 0, stream>>>(
      Xqc, WT, qc, kc, vcT, bq, bk, bv, nvpadA, 1024, 1024, 1024, 1024);

  // 5) scores (128^2 core): 8z * 16bm * 16bn = 2048 blocks
  gemm128<2><<<2048, 256, 0, stream>>>(
      qc, kc, scores, nvp128A, nvA, idxA, 1024, 1024, 1024, 2048,
      (size_t)2048 * 1024, (size_t)2048 * 1024, (size_t)2048 * 2048);

  // 6) compacted softmax (in place); zero-fill to nvpad128
  softmaxc<<<dim3(2048, 8), 256, 0, stream>>>(scores, nvA, nvp128A);

  // 7) PV (128^2 core): 8z * 16bm * 8bn = 1024 blocks; K = nvpad128[z]
  gemm128<3><<<1024, 256, 0, stream>>>(
      scores, vcT, d_out, nvp128A, nvA, idxA, 0, 2048, 2048, 1024,
      (size_t)2048 * 2048, (size_t)1024 * 2048, 0);

  // 8) masked q-rows: out = vmean
  bcast<<<dim3(2048, 8), 256, 0, stream>>>(mask, vmean, (float*)d_out);
}

// Round 14
// 252.323 us; speedup vs baseline: 1.1197x; 1.0133x over previous
//
#include <hip/hip_runtime.h>
#include <stdint.h>

// SelfAttentionV3 with mask-compaction. B=8, S=2048, D=1024.
// R14: (1) projections sized on nvp128 (was nvpad256) — linear M-padding cut;
// (2) gemm128 (scores/PV) gets R2-verified 2-phase LDS double-buffer;
// (3) wtrans3+colpart merged into one dispatch.
// projAll stays on the 256^2 8-phase core; gemm128 is the R1 core + 2-phase.

typedef unsigned short u16;
typedef __attribute__((ext_vector_type(8))) short short8;
typedef __attribute__((ext_vector_type(4))) float f32x4;

__device__ __forceinline__ u16 f2bf(float x) {
  unsigned u = __float_as_uint(x);
  return (u16)((u + 0x7FFFu + ((u >> 16) & 1u)) >> 16);  // RNE
}
__device__ __forceinline__ float bf2f(u16 h) {
  return __uint_as_float(((unsigned)h) << 16);
}

__device__ __forceinline__ void stage16(const void* g, void* l) {
  const __attribute__((address_space(1))) uint32_t* gp =
      (const __attribute__((address_space(1))) uint32_t*)(uintptr_t)g;
  __attribute__((address_space(3))) uint32_t* lp =
      (__attribute__((address_space(3))) uint32_t*)(uintptr_t)l;
  __builtin_amdgcn_global_load_lds(gp, lp, 16, 0, 0);
}

__device__ __forceinline__ short8 ld8(const char* p, int off) {
  return *(const short8*)(p + off);
}

// ---- mask prefix-scan: per batch -> idx list, nv, nvp128 ----
__global__ __launch_bounds__(256) void maskscan(const int* __restrict__ mask,
                                                int* __restrict__ idxA,
                                                int* __restrict__ nvA,
                                                int* __restrict__ nvp128A) {
  const int b = blockIdx.x;
  const int t = threadIdx.x, lane = t & 63, w = t >> 6;
  const int* m = mask + b * 2048;
  int v[8], loc = 0;
#pragma unroll
  for (int i = 0; i < 8; ++i) { v[i] = m[t * 8 + i]; loc += v[i]; }
  int sc = loc;  // inclusive scan over 64 lanes
  for (int off = 1; off < 64; off <<= 1) {
    int n = __shfl_up(sc, off);
    if (lane >= off) sc += n;
  }
  __shared__ int wsum[4];
  if (lane == 63) wsum[w] = sc;
  __syncthreads();
  int woff = 0;
  for (int i = 0; i < w; ++i) woff += wsum[i];
  int pos = woff + sc - loc;  // exclusive prefix
#pragma unroll
  for (int i = 0; i < 8; ++i)
    if (v[i]) idxA[b * 2048 + (pos++)] = t * 8 + i;
  if (t == 255) {
    const int nv = woff + sc;
    nvA[b] = nv;
    nvp128A[b] = (nv + 127) & ~127;
  }
}

// ---- fused gather+convert for q,k,v (z selects input) ----
__global__ __launch_bounds__(256) void compact3(const float* __restrict__ Xq,
                                                const float* __restrict__ Xk,
                                                const float* __restrict__ Xv,
                                                const int* __restrict__ idxA,
                                                const int* __restrict__ nvA,
                                                u16* __restrict__ Oq,
                                                u16* __restrict__ Ok,
                                                u16* __restrict__ Ov) {
  const int b = blockIdx.y, j = blockIdx.x, z = blockIdx.z;
  if (j >= nvA[b]) return;
  const float* X = (z == 0) ? Xq : (z == 1) ? Xk : Xv;
  u16* out = (z == 0) ? Oq : (z == 1) ? Ok : Ov;
  const int src = idxA[b * 2048 + j];
  const float4* s = (const float4*)(X + ((size_t)b * 2048 + src) * 1024);
  ushort4* d = (ushort4*)(out + ((size_t)b * 2048 + j) * 1024);
  const float4 f = s[threadIdx.x];
  ushort4 o;
  o.x = f2bf(f.x); o.y = f2bf(f.y); o.z = f2bf(f.z); o.w = f2bf(f.w);
  d[threadIdx.x] = o;
}

// ---- merged: wtrans (blocks 0..3071) + colpart (blocks 3072..3327) ----
__global__ __launch_bounds__(256) void wtcol(const float* __restrict__ Wq,
                                             const float* __restrict__ Wk,
                                             const float* __restrict__ Wv,
                                             u16* __restrict__ WT,
                                             const float* __restrict__ Xv,
                                             float* __restrict__ partial) {
  const int bid = blockIdx.x;
  const int t = threadIdx.x;
  if (bid < 3072) {
    // weight transpose: z = bid/1024, 32x32 tile grid within
    __shared__ float tile[32][33];
    const int z = bid >> 10;
    const int xy = bid & 1023;
    const int n0 = (xy & 31) * 32, d0 = (xy >> 5) * 32;
    const float* W = (z == 0) ? Wq : (z == 1) ? Wk : Wv;
    u16* out = WT + (size_t)z * 1024 * 1024;
    const int tx = t & 31, ty = t >> 5;  // 32 x 8
#pragma unroll
    for (int i = 0; i < 4; ++i)
      tile[ty + 8 * i][tx] = W[(size_t)(d0 + ty + 8 * i) * 1024 + n0 + tx];
    __syncthreads();
#pragma unroll
    for (int i = 0; i < 4; ++i)
      out[(size_t)(n0 + ty + 8 * i) * 1024 + d0 + tx] = f2bf(tile[tx][ty + 8 * i]);
  } else {
    // colpart: r in [0,256): b = r&7, dq = (r>>3)&3, sck = r>>5
    const int r = bid - 3072;
    const int b = r & 7, dq = (r >> 3) & 3, sck = r >> 5;
    const int d = dq * 256 + t;
    const float* p = Xv + ((size_t)b * 2048 + sck * 256) * 1024 + d;
    float s0 = 0, s1 = 0, s2 = 0, s3 = 0;
    for (int rr = 0; rr < 256; rr += 4) {
      s0 += p[(size_t)(rr + 0) * 1024];
      s1 += p[(size_t)(rr + 1) * 1024];
      s2 += p[(size_t)(rr + 2) * 1024];
      s3 += p[(size_t)(rr + 3) * 1024];
    }
    partial[((size_t)b * 8 + sck) * 1024 + d] = (s0 + s1) + (s2 + s3);
  }
}

// ---- vpart[b][dk][c] = sum_{d in chunk} meanX[b][d]*Wv[d][c]; meanX folded ----
__global__ __launch_bounds__(256) void vpartk(const float* __restrict__ partial,
                                              const float* __restrict__ Wv,
                                              float* __restrict__ vpart) {
  const int b = blockIdx.x, cq = blockIdx.y, dk = blockIdx.z;
  const int t = threadIdx.x;
  __shared__ float mx[128];
  if (t < 128) {
    const int d = dk * 128 + t;
    float m = 0;
#pragma unroll
    for (int i = 0; i < 8; ++i) m += partial[((size_t)b * 8 + i) * 1024 + d];
    mx[t] = m * (1.0f / 2048.0f);
  }
  __syncthreads();
  const int c = cq * 256 + t;
  const float* wp = Wv + (size_t)(dk * 128) * 1024 + c;
  float acc = 0;
#pragma unroll 4
  for (int i = 0; i < 128; ++i) acc += mx[i] * wp[(size_t)i * 1024];
  vpart[((size_t)b * 8 + dk) * 1024 + c] = acc;
}

// ---- vmean[b][c] = bv[c] + sum_dk vpart[b][dk][c] ----
__global__ __launch_bounds__(256) void vmeanred(const float* __restrict__ vpart,
                                                const float* __restrict__ bv,
                                                float* __restrict__ vmean) {
  const int b = blockIdx.x;
  const int c = blockIdx.y * 256 + threadIdx.x;
  float acc = bv[c];
#pragma unroll
  for (int i = 0; i < 8; ++i) acc += vpart[((size_t)b * 8 + i) * 1024 + c];
  vmean[b * 1024 + c] = acc;
}

// ---- out rows for masked q: broadcast vmean ----
__global__ __launch_bounds__(256) void bcast(const int* __restrict__ mask,
                                             const float* __restrict__ vmean,
                                             float* __restrict__ out) {
  const int b = blockIdx.y, row = blockIdx.x;
  if (mask[b * 2048 + row] != 0) return;
  const float4 vv = ((const float4*)(vmean + b * 1024))[threadIdx.x];
  ((float4*)(out + ((size_t)b * 2048 + row) * 1024))[threadIdx.x] = vv;
}

// ================= 256x256 8-phase core: projections only =================
#define BAR __builtin_amdgcn_s_barrier()
#define SB __builtin_amdgcn_sched_barrier(0)
#define LGK0 asm volatile("s_waitcnt lgkmcnt(0)" ::: "memory")
#define VM4 asm volatile("s_waitcnt vmcnt(4)" ::: "memory")
#define VM0 asm volatile("s_waitcnt vmcnt(0)" ::: "memory")

#define RDA4(P0, P1, MH)                                      \
  {                                                           \
    _Pragma("unroll") for (int mf_ = 0; mf_ < 4; ++mf_) {     \
      afr[0][mf_] = ld8(P0, (MH) * 8192 + mf_ * 2048);        \
      afr[1][mf_] = ld8(P1, (MH) * 8192 + mf_ * 2048);        \
    }                                                         \
  }

#define RDB2(DST, P0, P1, NH)                                 \
  {                                                           \
    DST[0][0] = ld8(P0, (NH) * 4096);                         \
    DST[0][1] = ld8(P0, (NH) * 4096 + 2048);                  \
    DST[1][0] = ld8(P1, (NH) * 4096);                         \
    DST[1][1] = ld8(P1, (NH) * 4096 + 2048);                  \
  }

#define MQ16(ACC, NH, BF)                                                \
  __builtin_amdgcn_s_setprio(1);                                         \
  {                                                                      \
    _Pragma("unroll") for (int ks_ = 0; ks_ < 2; ++ks_)                  \
        _Pragma("unroll") for (int mf_ = 0; mf_ < 4; ++mf_)              \
            _Pragma("unroll") for (int nf_ = 0; nf_ < 2; ++nf_)          \
                ACC[mf_][(NH) * 2 + nf_] =                               \
                    __builtin_amdgcn_mfma_f32_16x16x32_bf16(             \
                        afr[ks_][mf_], BF[ks_][nf_],                     \
                        ACC[mf_][(NH) * 2 + nf_], 0, 0, 0);              \
  }                                                                      \
  __builtin_amdgcn_s_setprio(0);

// combined projections (o=0 q, 1 k, 2 v-transposed), early-exit on nvp128
__global__ __launch_bounds__(512, 2) void gemm8p(
    const u16* __restrict__ A, const u16* __restrict__ B,
    void* __restrict__ C, void* __restrict__ C1, void* __restrict__ C2,
    const float* __restrict__ b0, const float* __restrict__ b1,
    const float* __restrict__ b2,
    const int* __restrict__ nvp128A,
    int K, int lda, int ldb, int ldc) {
  __shared__ __attribute__((aligned(16))) char smem[131072];
  const int tid = threadIdx.x;
  const int lane = tid & 63;
  const int w = tid >> 6;
  const int wr = w >> 2;
  const int wc = w & 3;

  const int bx = blockIdx.x;
  const int z = bx & 7;
  int r = bx >> 3;
  const int o = r >> 5; r &= 31;
  const int bm = r >> 2, bn = r & 3;

  const int nvp = nvp128A[z];
  if (bm * 256 >= nvp) return;

  const u16* Ap = A + (size_t)o * (8u * 2048u * 1024u) + (size_t)z * (2048u * 1024u);
  const u16* Bp = B + (size_t)o * (1024u * 1024u);
  const int half = K >> 7;

  const int srow = w * 8 + (lane >> 3);
  const int scol = ((lane & 7) ^ (lane >> 3)) << 3;  // elems
  const u16* Ab0 = Ap + (size_t)(bm * 256 + srow) * lda + scol;
  const u16* Ab1 = Ab0 + (size_t)64 * lda;
  const u16* Ab2 = Ab0 + (size_t)128 * lda;
  const u16* Ab3 = Ab0 + (size_t)192 * lda;
  const u16* Bb0 = Bp + (size_t)(bn * 256 + srow) * ldb + scol;
  const u16* Bb1 = Bb0 + (size_t)64 * ldb;
  const u16* Bb2 = Bb0 + (size_t)128 * ldb;
  const u16* Bb3 = Bb0 + (size_t)192 * ldb;
  char* ldsW = smem + w * 1024;

  const int fr = lane & 15;
  const int fq = lane >> 4;
  const int fx = (fr & 7) << 4;
  const char* pak0 = smem + wr * 16384 + fr * 128 + ((fq * 16) ^ fx);
  const char* pak1 = smem + wr * 16384 + fr * 128 + ((64 + fq * 16) ^ fx);
  const char* pak0b = pak0 + 65536;
  const char* pak1b = pak1 + 65536;
  const char* pbk0 = smem + 32768 + wc * 8192 + fr * 128 + ((fq * 16) ^ fx);
  const char* pbk1 = smem + 32768 + wc * 8192 + fr * 128 + ((64 + fq * 16) ^ fx);
  const char* pbk0b = pbk0 + 65536;
  const char* pbk1b = pbk1 + 65536;

  f32x4 acc0[4][4] = {};
  f32x4 acc1[4][4] = {};
  short8 afr[2][4], bf0[2][2], bf1[2][2];

  stage16(Bb0, ldsW + 32768); stage16(Bb1, ldsW + 40960);
  stage16(Bb2, ldsW + 49152); stage16(Bb3, ldsW + 57344);
  stage16(Ab0, ldsW + 0);     stage16(Ab1, ldsW + 8192);
  stage16(Ab2, ldsW + 16384); stage16(Ab3, ldsW + 24576);
  stage16(Bb0 + 64, ldsW + 98304);  stage16(Bb1 + 64, ldsW + 106496);
  stage16(Bb2 + 64, ldsW + 114688); stage16(Bb3 + 64, ldsW + 122880);
  VM4;
  BAR;

  int koff = 0;
  for (int i = 0; i < half - 1; ++i) {
    const int o1 = koff + 64, o2 = koff + 128, o3 = koff + 192;
    RDA4(pak0, pak1, 0); RDB2(bf0, pbk0, pbk1, 0);
    stage16(Ab0 + o1, ldsW + 65536); stage16(Ab1 + o1, ldsW + 73728);
    SB; BAR; LGK0; MQ16(acc0, 0, bf0); BAR;
    RDB2(bf1, pbk0, pbk1, 1);
    stage16(Ab2 + o1, ldsW + 81920); stage16(Ab3 + o1, ldsW + 90112);
    SB; BAR; LGK0; MQ16(acc0, 1, bf1); BAR;
    RDA4(pak0, pak1, 1);
    stage16(Bb0 + o2, ldsW + 32768); stage16(Bb1 + o2, ldsW + 40960);
    SB; BAR; LGK0; MQ16(acc1, 0, bf0); BAR;
    stage16(Bb2 + o2, ldsW + 49152); stage16(Bb3 + o2, ldsW + 57344);
    SB; BAR; MQ16(acc1, 1, bf1); VM4; BAR;
    RDA4(pak0b, pak1b, 0); RDB2(bf0, pbk0b, pbk1b, 0);
    stage16(Ab0 + o2, ldsW + 0); stage16(Ab1 + o2, ldsW + 8192);
    SB; BAR; LGK0; MQ16(acc0, 0, bf0); BAR;
    RDB2(bf1, pbk0b, pbk1b, 1);
    stage16(Ab2 + o2, ldsW + 16384); stage16(Ab3 + o2, ldsW + 24576);
    SB; BAR; LGK0; MQ16(acc0, 1, bf1); BAR;
    RDA4(pak0b, pak1b, 1);
    stage16(Bb0 + o3, ldsW + 98304); stage16(Bb1 + o3, ldsW + 106496);
    SB; BAR; LGK0; MQ16(acc1, 0, bf0); BAR;
    stage16(Bb2 + o3, ldsW + 114688); stage16(Bb3 + o3, ldsW + 122880);
    SB; BAR; MQ16(acc1, 1, bf1); VM4; BAR;
    koff += 128;
  }
  {
    const int o1 = koff + 64;
    RDA4(pak0, pak1, 0); RDB2(bf0, pbk0, pbk1, 0);
    stage16(Ab0 + o1, ldsW + 65536); stage16(Ab1 + o1, ldsW + 73728);
    SB; BAR; LGK0; MQ16(acc0, 0, bf0); BAR;
    RDB2(bf1, pbk0, pbk1, 1);
    stage16(Ab2 + o1, ldsW + 81920); stage16(Ab3 + o1, ldsW + 90112);
    SB; BAR; LGK0; MQ16(acc0, 1, bf1); BAR;
    RDA4(pak0, pak1, 1);
    SB; BAR; LGK0; MQ16(acc1, 0, bf0); BAR;
    SB; BAR; MQ16(acc1, 1, bf1); VM0; BAR;
    RDA4(pak0b, pak1b, 0); RDB2(bf0, pbk0b, pbk1b, 0);
    SB; BAR; LGK0; MQ16(acc0, 0, bf0); BAR;
    RDB2(bf1, pbk0b, pbk1b, 1);
    SB; BAR; LGK0; MQ16(acc0, 1, bf1); BAR;
    RDA4(pak0b, pak1b, 1);
    SB; BAR; LGK0; MQ16(acc1, 0, bf0); BAR;
    SB; BAR; MQ16(acc1, 1, bf1); BAR;
  }

  const int colb = bn * 256 + wc * 64 + fr;
#pragma unroll
  for (int mh = 0; mh < 2; ++mh) {
    f32x4(&ac)[4][4] = mh ? acc1 : acc0;
    const int rowl = bm * 256 + wr * 128 + mh * 64 + fq * 4;
    if (o < 2) {
      const float* bp = o ? b1 : b0;
      u16* Cb = (u16*)(o ? C1 : C) + (size_t)z * (2048u * 1024u);
#pragma unroll
      for (int mf = 0; mf < 4; ++mf)
#pragma unroll
        for (int n = 0; n < 4; ++n) {
          const int c = colb + n * 16;
          const float bv = bp[c];
#pragma unroll
          for (int j = 0; j < 4; ++j)
            Cb[(size_t)(rowl + mf * 16 + j) * ldc + c] = f2bf(ac[mf][n][j] + bv);
        }
    } else {
      u16* Cb = (u16*)C2;  // vcT [8][1024][2048]
#pragma unroll
      for (int mf = 0; mf < 4; ++mf) {
        const int s_ = rowl + mf * 16;
#pragma unroll
        for (int n = 0; n < 4; ++n) {
          const int c = colb + n * 16;
          const float bv = b2[c];
          ushort4 ov;
          ov.x = f2bf(ac[mf][n][0] + bv);
          ov.y = f2bf(ac[mf][n][1] + bv);
          ov.z = f2bf(ac[mf][n][2] + bv);
          ov.w = f2bf(ac[mf][n][3] + bv);
          *(ushort4*)&Cb[((size_t)z * 1024 + c) * 2048 + s_] = ov;
        }
      }
    }
  }
}

// ======= 128x128/BK32 4-wave core + 2-phase double-buffer: scores & PV ======
// MODE 2: scores = qc kc^T /32 (bf16 out). MODE 3: PV -> d_out scatter (fp32).
template <int MODE>
__global__ __launch_bounds__(256, 2) void gemm128(
    const u16* __restrict__ A, const u16* __restrict__ B, void* __restrict__ C,
    const int* __restrict__ nvp128A, const int* __restrict__ nvA,
    const int* __restrict__ idxA,
    int K, int lda, int ldb, int ldc,
    size_t Az, size_t Bz, size_t Cz) {
  __shared__ __attribute__((aligned(16))) u16 lsA[2 * 128 * 32];
  __shared__ __attribute__((aligned(16))) u16 lsB[2 * 128 * 32];
  const int tid = threadIdx.x;
  const int lane = tid & 63;
  const int w = tid >> 6;      // 0..3
  const int wr = w >> 1, wc = w & 1;

  const int bx = blockIdx.x;
  const int z = bx & 7;
  const int r = bx >> 3;
  int bm, bn;
  if constexpr (MODE == 2) { bm = r >> 4; bn = r & 15; }   // 16 x 16
  else                     { bm = r >> 3; bn = r & 7; }    // 16 x 8

  const int nvp = nvp128A[z];
  if (bm * 128 >= nvp) return;
  if constexpr (MODE == 2) { if (bn * 128 >= nvp) return; }
  const int Kz = (MODE == 3) ? nvp : K;

  const u16* Ap = A + (size_t)z * Az;
  const u16* Bp = B + (size_t)z * Bz;

  // staging: wave w stages rows [w*32, w*32+32); one stage16 = 16 rows.
  const int srow = lane >> 2;
  const int scol = (lane & 3) * 8;
  const u16* Ag0 = Ap + (size_t)(bm * 128 + w * 32 + srow) * lda + scol;
  const u16* Ag1 = Ag0 + (size_t)16 * lda;
  const u16* Bg0 = Bp + (size_t)(bn * 128 + w * 32 + srow) * ldb + scol;
  const u16* Bg1 = Bg0 + (size_t)16 * ldb;
  u16* lA0 = &lsA[(w * 32) * 32];
  u16* lA1 = &lsA[(w * 32 + 16) * 32];
  u16* lB0 = &lsB[(w * 32) * 32];
  u16* lB1 = &lsB[(w * 32 + 16) * 32];

  const int arow = wr * 64 + (lane & 15);
  const int brow = wc * 64 + (lane & 15);
  const int ko = (lane >> 4) * 8;

  f32x4 acc[4][4] = {};

  auto compute = [&](int cur) {
    const u16* sA = lsA + cur * 4096;
    const u16* sB = lsB + cur * 4096;
    short8 af[4], bfr[4];
#pragma unroll
    for (int m = 0; m < 4; ++m)
      af[m] = *(const short8*)&sA[(arow + m * 16) * 32 + ko];
#pragma unroll
    for (int n = 0; n < 4; ++n)
      bfr[n] = *(const short8*)&sB[(brow + n * 16) * 32 + ko];
#pragma unroll
    for (int m = 0; m < 4; ++m)
#pragma unroll
      for (int n = 0; n < 4; ++n)
        acc[m][n] =
            __builtin_amdgcn_mfma_f32_16x16x32_bf16(af[m], bfr[n], acc[m][n], 0, 0, 0);
  };

  // prologue: K-tile 0 -> buf 0
  stage16(Ag0, lA0);
  stage16(Ag1, lA1);
  stage16(Bg0, lB0);
  stage16(Bg1, lB1);
  __syncthreads();  // vmcnt(0) + barrier

  int cur = 0;
  int k0 = 0;
  for (; k0 + 32 < Kz; k0 += 32) {
    const int off = (cur ^ 1) * 4096;
    const int kn = k0 + 32;
    stage16(Ag0 + kn, lA0 + off);  // issue next tile first (overlaps compute)
    stage16(Ag1 + kn, lA1 + off);
    stage16(Bg0 + kn, lB0 + off);
    stage16(Bg1 + kn, lB1 + off);
    compute(cur);
    __syncthreads();  // drains vmcnt; protects buf reuse
    cur ^= 1;
  }
  compute(cur);  // last tile

  // D layout: col = lane&15 (+n*16), row = (lane>>4)*4 + j (+m*16)
  const int col0 = bn * 128 + wc * 64 + (lane & 15);
  const int row0 = bm * 128 + wr * 64 + ((lane >> 4) << 2);

  if constexpr (MODE == 2) {
    u16* Cb = (u16*)C + (size_t)z * Cz;
#pragma unroll
    for (int m = 0; m < 4; ++m)
#pragma unroll
      for (int n = 0; n < 4; ++n) {
        const int c = col0 + n * 16;
#pragma unroll
        for (int j = 0; j < 4; ++j)
          Cb[(size_t)(row0 + m * 16 + j) * ldc + c] =
              f2bf(acc[m][n][j] * 0.03125f);
      }
  } else {  // MODE 3: scatter rows < nv via idx
    const int nv = nvA[z];
    const int* idxp = idxA + z * 2048;
    float* Ob = (float*)C;
#pragma unroll
    for (int m = 0; m < 4; ++m)
#pragma unroll
      for (int j = 0; j < 4; ++j) {
        const int rowc = row0 + m * 16 + j;
        if (rowc < nv) {
          const int gr = idxp[rowc];
          float* orow = Ob + ((size_t)z * 2048 + gr) * 1024;
#pragma unroll
          for (int n = 0; n < 4; ++n) orow[col0 + n * 16] = acc[m][n][j];
        }
      }
  }
}

// ---- softmax on compacted rows: cols < nv softmaxed, [nv, nvp128) zeroed ----
__global__ __launch_bounds__(256) void softmaxc(u16* __restrict__ scores,
                                                const int* __restrict__ nvA,
                                                const int* __restrict__ nvp128A) {
  const int b = blockIdx.y, row = blockIdx.x;
  const int nv = nvA[b];
  if (row >= nv) return;
  const int nvp = nvp128A[b];
  const int t = threadIdx.x, lane = t & 63, w = t >> 6;
  u16* sc = scores + ((size_t)b * 2048 + row) * 2048;
  const int c0 = t * 8;
  float v[8];
  if (c0 < nvp) {
    const ushort4 h0 = *(const ushort4*)&sc[c0];
    const ushort4 h1 = *(const ushort4*)&sc[c0 + 4];
    v[0] = bf2f(h0.x); v[1] = bf2f(h0.y); v[2] = bf2f(h0.z); v[3] = bf2f(h0.w);
    v[4] = bf2f(h1.x); v[5] = bf2f(h1.y); v[6] = bf2f(h1.z); v[7] = bf2f(h1.w);
  } else {
#pragma unroll
    for (int i = 0; i < 8; ++i) v[i] = 0.f;
  }
  float lmax = -3.0e38f;
#pragma unroll
  for (int i = 0; i < 8; ++i)
    if (c0 + i < nv) lmax = fmaxf(lmax, v[i]);
#pragma unroll
  for (int off = 32; off >= 1; off >>= 1) lmax = fmaxf(lmax, __shfl_xor(lmax, off));
  __shared__ float red[8];
  if (lane == 0) red[w] = lmax;
  __syncthreads();
  const float bmax = fmaxf(fmaxf(red[0], red[1]), fmaxf(red[2], red[3]));
  float e[8];
  float lsum = 0.f;
#pragma unroll
  for (int i = 0; i < 8; ++i) {
    e[i] = (c0 + i < nv) ? __expf(v[i] - bmax) : 0.f;
    lsum += e[i];
  }
#pragma unroll
  for (int off = 32; off >= 1; off >>= 1) lsum += __shfl_xor(lsum, off);
  if (lane == 0) red[4 + w] = lsum;
  __syncthreads();
  const float inv = 1.0f / ((red[4] + red[5]) + (red[6] + red[7]));
  if (c0 < nvp) {
    ushort4 o0, o1;
    o0.x = f2bf(e[0] * inv); o0.y = f2bf(e[1] * inv);
    o0.z = f2bf(e[2] * inv); o0.w = f2bf(e[3] * inv);
    o1.x = f2bf(e[4] * inv); o1.y = f2bf(e[5] * inv);
    o1.z = f2bf(e[6] * inv); o1.w = f2bf(e[7] * inv);
    *(ushort4*)&sc[c0] = o0;
    *(ushort4*)&sc[c0 + 4] = o1;
  }
}

extern "C" void kernel_launch(void* const* d_in, const int* in_sizes, int n_in,
                              void* d_out, int out_size, void* d_ws, size_t ws_size,
                              hipStream_t stream) {
  const float* in_q = (const float*)d_in[0];
  const float* in_k = (const float*)d_in[1];
  const float* in_v = (const float*)d_in[2];
  const int* mask = (const int*)d_in[3];
  const float* Wq = (const float*)d_in[4];
  const float* bq = (const float*)d_in[5];
  const float* Wk = (const float*)d_in[6];
  const float* bk = (const float*)d_in[7];
  const float* Wv = (const float*)d_in[8];
  const float* bv = (const float*)d_in[9];

  char* ws = (char*)d_ws;
  const size_t SZ = (size_t)16384 * 1024 * 2;  // 32M bytes
  u16* qc = (u16*)(ws);
  u16* kc = (u16*)(ws + SZ);
  u16* vcT = (u16*)(ws + 2 * SZ);
  u16* Xc = (u16*)(ws + 3 * SZ);        // Xqc, Xkc, Xvc (32M each)
  u16* Xqc = Xc;
  u16* Xkc = Xc + (size_t)8 * 2048 * 1024;
  u16* Xvc = Xkc + (size_t)8 * 2048 * 1024;
  u16* scores = (u16*)(ws + 3 * SZ);    // overlays Xc after projections
  u16* WT = (u16*)(ws + 6 * SZ);        // WqT, WkT, WvT contiguous
  char* misc = ws + 6 * SZ + 6 * 1024 * 1024;
  int* idxA = (int*)misc;               // [8][2048] = 64KB
  int* nvA = idxA + 8 * 2048;
  int* nvp128A = nvA + 8;
  float* partial = (float*)(misc + 128 * 1024);  // [8][8][1024] = 256KB
  float* vmean = (float*)(misc + 384 * 1024);    // [8][1024] = 32KB
  float* vpart = (float*)(misc + 448 * 1024);    // [8][8][1024] = 256KB

  // 1) mask scan -> idx, nv, nvp128
  maskscan<<<8, 256, 0, stream>>>(mask, idxA, nvA, nvp128A);

  // 2) fused gather+convert; merged wtrans+colpart; vmean path
  compact3<<<dim3(2048, 8, 3), 256, 0, stream>>>(in_q, in_k, in_v, idxA, nvA,
                                                 Xqc, Xkc, Xvc);
  wtcol<<<3328, 256, 0, stream>>>(Wq, Wk, Wv, WT, in_v, partial);
  vpartk<<<dim3(8, 4, 8), 256, 0, stream>>>(partial, Wv, vpart);
  vmeanred<<<dim3(8, 4), 256, 0, stream>>>(vpart, bv, vmean);

  // 3) all three projections (256^2 core, nvp128-sized): 768 blocks
  gemm8p<<<768, 512, 0, stream>>>(
      Xqc, WT, qc, kc, vcT, bq, bk, bv, nvp128A, 1024, 1024, 1024, 1024);

  // 4) scores (128^2 2-phase core): 8z * 16bm * 16bn = 2048 blocks
  gemm128<2><<<2048, 256, 0, stream>>>(
      qc, kc, scores, nvp128A, nvA, idxA, 1024, 1024, 1024, 2048,
      (size_t)2048 * 1024, (size_t)2048 * 1024, (size_t)2048 * 2048);

  // 5) compacted softmax (in place); zero-fill to nvp128
  softmaxc<<<dim3(2048, 8), 256, 0, stream>>>(scores, nvA, nvp128A);

  // 6) PV (128^2 2-phase core): 8z * 16bm * 8bn = 1024 blocks; K = nvp128[z]
  gemm128<3><<<1024, 256, 0, stream>>>(
      scores, vcT, d_out, nvp128A, nvA, idxA, 0, 2048, 2048, 1024,
      (size_t)2048 * 2048, (size_t)1024 * 2048, 0);

  // 7) masked q-rows: out = vmean
  bcast<<<dim3(2048, 8), 256, 0, stream>>>(mask, vmean, (float*)d_out);
}

// Round 15
// 230.649 us; speedup vs baseline: 1.2249x; 1.0940x over previous
//
#include <hip/hip_runtime.h>
#include <stdint.h>

// SelfAttentionV3 with mask-compaction. B=8, S=2048, D=1024.
// R15: dispatch-count reduction 9 -> 6 (Amdahl on launch gaps + tail fill):
//   scanwt  = maskscan + wtrans3 + colpart      (1 dispatch)
//   compact3 reworked to 4 rows/block (one per wave)
//   projAll (gemm8p) += vpartk aux blocks (fills its 1.875-round tail)
//   scores (gemm128<2>) += vmeanred aux blocks
//   softbc  = softmaxc (z=0) + bcast (z=1)
// GEMM inner loops are byte-identical to R14 (3 nulls on schedule surgery).

typedef unsigned short u16;
typedef __attribute__((ext_vector_type(8))) short short8;
typedef __attribute__((ext_vector_type(4))) float f32x4;

__device__ __forceinline__ u16 f2bf(float x) {
  unsigned u = __float_as_uint(x);
  return (u16)((u + 0x7FFFu + ((u >> 16) & 1u)) >> 16);  // RNE
}
__device__ __forceinline__ float bf2f(u16 h) {
  return __uint_as_float(((unsigned)h) << 16);
}

__device__ __forceinline__ void stage16(const void* g, void* l) {
  const __attribute__((address_space(1))) uint32_t* gp =
      (const __attribute__((address_space(1))) uint32_t*)(uintptr_t)g;
  __attribute__((address_space(3))) uint32_t* lp =
      (__attribute__((address_space(3))) uint32_t*)(uintptr_t)l;
  __builtin_amdgcn_global_load_lds(gp, lp, 16, 0, 0);
}

__device__ __forceinline__ short8 ld8(const char* p, int off) {
  return *(const short8*)(p + off);
}

// ---- merged: maskscan (0..7) + wtrans (8..3079) + colpart (3080..3335) ----
__global__ __launch_bounds__(256) void scanwt(const int* __restrict__ mask,
                                              int* __restrict__ idxA,
                                              int* __restrict__ nvA,
                                              int* __restrict__ nvp128A,
                                              const float* __restrict__ Wq,
                                              const float* __restrict__ Wk,
                                              const float* __restrict__ Wv,
                                              u16* __restrict__ WT,
                                              const float* __restrict__ Xv,
                                              float* __restrict__ partial) {
  __shared__ int wsum[4];
  __shared__ float tile[32][33];
  const int bid = blockIdx.x;
  const int t = threadIdx.x;
  if (bid < 8) {
    // maskscan: per batch -> idx list, nv, nvp128
    const int b = bid;
    const int lane = t & 63, w = t >> 6;
    const int* m = mask + b * 2048;
    int v[8], loc = 0;
#pragma unroll
    for (int i = 0; i < 8; ++i) { v[i] = m[t * 8 + i]; loc += v[i]; }
    int sc = loc;
    for (int off = 1; off < 64; off <<= 1) {
      int n = __shfl_up(sc, off);
      if (lane >= off) sc += n;
    }
    if (lane == 63) wsum[w] = sc;
    __syncthreads();
    int woff = 0;
    for (int i = 0; i < w; ++i) woff += wsum[i];
    int pos = woff + sc - loc;
#pragma unroll
    for (int i = 0; i < 8; ++i)
      if (v[i]) idxA[b * 2048 + (pos++)] = t * 8 + i;
    if (t == 255) {
      const int nv = woff + sc;
      nvA[b] = nv;
      nvp128A[b] = (nv + 127) & ~127;
    }
  } else if (bid < 3080) {
    // weight transpose
    const int q = bid - 8;
    const int z = q >> 10;
    const int xy = q & 1023;
    const int n0 = (xy & 31) * 32, d0 = (xy >> 5) * 32;
    const float* W = (z == 0) ? Wq : (z == 1) ? Wk : Wv;
    u16* out = WT + (size_t)z * 1024 * 1024;
    const int tx = t & 31, ty = t >> 5;  // 32 x 8
#pragma unroll
    for (int i = 0; i < 4; ++i)
      tile[ty + 8 * i][tx] = W[(size_t)(d0 + ty + 8 * i) * 1024 + n0 + tx];
    __syncthreads();
#pragma unroll
    for (int i = 0; i < 4; ++i)
      out[(size_t)(n0 + ty + 8 * i) * 1024 + d0 + tx] = f2bf(tile[tx][ty + 8 * i]);
  } else {
    // colpart: column partial sums of Xv
    const int r = bid - 3080;
    const int b = r & 7, dq = (r >> 3) & 3, sck = r >> 5;
    const int d = dq * 256 + t;
    const float* p = Xv + ((size_t)b * 2048 + sck * 256) * 1024 + d;
    float s0 = 0, s1 = 0, s2 = 0, s3 = 0;
    for (int rr = 0; rr < 256; rr += 4) {
      s0 += p[(size_t)(rr + 0) * 1024];
      s1 += p[(size_t)(rr + 1) * 1024];
      s2 += p[(size_t)(rr + 2) * 1024];
      s3 += p[(size_t)(rr + 3) * 1024];
    }
    partial[((size_t)b * 8 + sck) * 1024 + d] = (s0 + s1) + (s2 + s3);
  }
}

// ---- fused gather+convert: 4 rows/block (one per wave), z selects input ----
__global__ __launch_bounds__(256) void compact3(const float* __restrict__ Xq,
                                                const float* __restrict__ Xk,
                                                const float* __restrict__ Xv,
                                                const int* __restrict__ idxA,
                                                const int* __restrict__ nvA,
                                                u16* __restrict__ Oq,
                                                u16* __restrict__ Ok,
                                                u16* __restrict__ Ov) {
  const int b = blockIdx.y, z = blockIdx.z;
  const int w = threadIdx.x >> 6, lane = threadIdx.x & 63;
  const int j = blockIdx.x * 4 + w;
  if (j >= nvA[b]) return;
  const float* X = (z == 0) ? Xq : (z == 1) ? Xk : Xv;
  u16* out = (z == 0) ? Oq : (z == 1) ? Ok : Ov;
  const int src = idxA[b * 2048 + j];
  const float4* s = (const float4*)(X + ((size_t)b * 2048 + src) * 1024);
  ushort4* d = (ushort4*)(out + ((size_t)b * 2048 + j) * 1024);
#pragma unroll
  for (int p = 0; p < 4; ++p) {
    const float4 f = s[lane + p * 64];
    ushort4 o;
    o.x = f2bf(f.x); o.y = f2bf(f.y); o.z = f2bf(f.z); o.w = f2bf(f.w);
    d[lane + p * 64] = o;
  }
}

// ================= 256x256 8-phase core: projections (+vpartk aux) ==========
#define BAR __builtin_amdgcn_s_barrier()
#define SB __builtin_amdgcn_sched_barrier(0)
#define LGK0 asm volatile("s_waitcnt lgkmcnt(0)" ::: "memory")
#define VM4 asm volatile("s_waitcnt vmcnt(4)" ::: "memory")
#define VM0 asm volatile("s_waitcnt vmcnt(0)" ::: "memory")

#define RDA4(P0, P1, MH)                                      \
  {                                                           \
    _Pragma("unroll") for (int mf_ = 0; mf_ < 4; ++mf_) {     \
      afr[0][mf_] = ld8(P0, (MH) * 8192 + mf_ * 2048);        \
      afr[1][mf_] = ld8(P1, (MH) * 8192 + mf_ * 2048);        \
    }                                                         \
  }

#define RDB2(DST, P0, P1, NH)                                 \
  {                                                           \
    DST[0][0] = ld8(P0, (NH) * 4096);                         \
    DST[0][1] = ld8(P0, (NH) * 4096 + 2048);                  \
    DST[1][0] = ld8(P1, (NH) * 4096);                         \
    DST[1][1] = ld8(P1, (NH) * 4096 + 2048);                  \
  }

#define MQ16(ACC, NH, BF)                                                \
  __builtin_amdgcn_s_setprio(1);                                         \
  {                                                                      \
    _Pragma("unroll") for (int ks_ = 0; ks_ < 2; ++ks_)                  \
        _Pragma("unroll") for (int mf_ = 0; mf_ < 4; ++mf_)              \
            _Pragma("unroll") for (int nf_ = 0; nf_ < 2; ++nf_)          \
                ACC[mf_][(NH) * 2 + nf_] =                               \
                    __builtin_amdgcn_mfma_f32_16x16x32_bf16(             \
                        afr[ks_][mf_], BF[ks_][nf_],                     \
                        ACC[mf_][(NH) * 2 + nf_], 0, 0, 0);              \
  }                                                                      \
  __builtin_amdgcn_s_setprio(0);

// combined projections (o=0 q, 1 k, 2 v-transposed); bx>=768 -> vpartk aux
__global__ __launch_bounds__(512, 2) void gemm8p(
    const u16* __restrict__ A, const u16* __restrict__ B,
    void* __restrict__ C, void* __restrict__ C1, void* __restrict__ C2,
    const float* __restrict__ b0, const float* __restrict__ b1,
    const float* __restrict__ b2,
    const int* __restrict__ nvp128A,
    const float* __restrict__ partial, const float* __restrict__ WvF,
    float* __restrict__ vpart,
    int K, int lda, int ldb, int ldc) {
  __shared__ __attribute__((aligned(16))) char smem[131072];

  // ---- aux region: vpartk (8b x 2cq x 8dk = 128 blocks) ----
  if (blockIdx.x >= 768) {
    float* mx = (float*)smem;  // 128 floats, overlaid
    const int r2 = blockIdx.x - 768;
    const int b = r2 & 7, cq = (r2 >> 3) & 1, dk = r2 >> 4;
    const int t = threadIdx.x;  // 0..511
    if (t < 128) {
      const int d = dk * 128 + t;
      float m = 0;
#pragma unroll
      for (int i = 0; i < 8; ++i) m += partial[((size_t)b * 8 + i) * 1024 + d];
      mx[t] = m * (1.0f / 2048.0f);
    }
    __syncthreads();
    const int c = cq * 512 + t;
    const float* wp = WvF + (size_t)(dk * 128) * 1024 + c;
    float acc = 0;
#pragma unroll 4
    for (int i = 0; i < 128; ++i) acc += mx[i] * wp[(size_t)i * 1024];
    vpart[((size_t)b * 8 + dk) * 1024 + c] = acc;
    return;
  }

  const int tid = threadIdx.x;
  const int lane = tid & 63;
  const int w = tid >> 6;
  const int wr = w >> 2;
  const int wc = w & 3;

  const int bx = blockIdx.x;
  const int z = bx & 7;
  int r = bx >> 3;
  const int o = r >> 5; r &= 31;
  const int bm = r >> 2, bn = r & 3;

  const int nvp = nvp128A[z];
  if (bm * 256 >= nvp) return;

  const u16* Ap = A + (size_t)o * (8u * 2048u * 1024u) + (size_t)z * (2048u * 1024u);
  const u16* Bp = B + (size_t)o * (1024u * 1024u);
  const int half = K >> 7;

  const int srow = w * 8 + (lane >> 3);
  const int scol = ((lane & 7) ^ (lane >> 3)) << 3;  // elems
  const u16* Ab0 = Ap + (size_t)(bm * 256 + srow) * lda + scol;
  const u16* Ab1 = Ab0 + (size_t)64 * lda;
  const u16* Ab2 = Ab0 + (size_t)128 * lda;
  const u16* Ab3 = Ab0 + (size_t)192 * lda;
  const u16* Bb0 = Bp + (size_t)(bn * 256 + srow) * ldb + scol;
  const u16* Bb1 = Bb0 + (size_t)64 * ldb;
  const u16* Bb2 = Bb0 + (size_t)128 * ldb;
  const u16* Bb3 = Bb0 + (size_t)192 * ldb;
  char* ldsW = smem + w * 1024;

  const int fr = lane & 15;
  const int fq = lane >> 4;
  const int fx = (fr & 7) << 4;
  const char* pak0 = smem + wr * 16384 + fr * 128 + ((fq * 16) ^ fx);
  const char* pak1 = smem + wr * 16384 + fr * 128 + ((64 + fq * 16) ^ fx);
  const char* pak0b = pak0 + 65536;
  const char* pak1b = pak1 + 65536;
  const char* pbk0 = smem + 32768 + wc * 8192 + fr * 128 + ((fq * 16) ^ fx);
  const char* pbk1 = smem + 32768 + wc * 8192 + fr * 128 + ((64 + fq * 16) ^ fx);
  const char* pbk0b = pbk0 + 65536;
  const char* pbk1b = pbk1 + 65536;

  f32x4 acc0[4][4] = {};
  f32x4 acc1[4][4] = {};
  short8 afr[2][4], bf0[2][2], bf1[2][2];

  stage16(Bb0, ldsW + 32768); stage16(Bb1, ldsW + 40960);
  stage16(Bb2, ldsW + 49152); stage16(Bb3, ldsW + 57344);
  stage16(Ab0, ldsW + 0);     stage16(Ab1, ldsW + 8192);
  stage16(Ab2, ldsW + 16384); stage16(Ab3, ldsW + 24576);
  stage16(Bb0 + 64, ldsW + 98304);  stage16(Bb1 + 64, ldsW + 106496);
  stage16(Bb2 + 64, ldsW + 114688); stage16(Bb3 + 64, ldsW + 122880);
  VM4;
  BAR;

  int koff = 0;
  for (int i = 0; i < half - 1; ++i) {
    const int o1 = koff + 64, o2 = koff + 128, o3 = koff + 192;
    RDA4(pak0, pak1, 0); RDB2(bf0, pbk0, pbk1, 0);
    stage16(Ab0 + o1, ldsW + 65536); stage16(Ab1 + o1, ldsW + 73728);
    SB; BAR; LGK0; MQ16(acc0, 0, bf0); BAR;
    RDB2(bf1, pbk0, pbk1, 1);
    stage16(Ab2 + o1, ldsW + 81920); stage16(Ab3 + o1, ldsW + 90112);
    SB; BAR; LGK0; MQ16(acc0, 1, bf1); BAR;
    RDA4(pak0, pak1, 1);
    stage16(Bb0 + o2, ldsW + 32768); stage16(Bb1 + o2, ldsW + 40960);
    SB; BAR; LGK0; MQ16(acc1, 0, bf0); BAR;
    stage16(Bb2 + o2, ldsW + 49152); stage16(Bb3 + o2, ldsW + 57344);
    SB; BAR; MQ16(acc1, 1, bf1); VM4; BAR;
    RDA4(pak0b, pak1b, 0); RDB2(bf0, pbk0b, pbk1b, 0);
    stage16(Ab0 + o2, ldsW + 0); stage16(Ab1 + o2, ldsW + 8192);
    SB; BAR; LGK0; MQ16(acc0, 0, bf0); BAR;
    RDB2(bf1, pbk0b, pbk1b, 1);
    stage16(Ab2 + o2, ldsW + 16384); stage16(Ab3 + o2, ldsW + 24576);
    SB; BAR; LGK0; MQ16(acc0, 1, bf1); BAR;
    RDA4(pak0b, pak1b, 1);
    stage16(Bb0 + o3, ldsW + 98304); stage16(Bb1 + o3, ldsW + 106496);
    SB; BAR; LGK0; MQ16(acc1, 0, bf0); BAR;
    stage16(Bb2 + o3, ldsW + 114688); stage16(Bb3 + o3, ldsW + 122880);
    SB; BAR; MQ16(acc1, 1, bf1); VM4; BAR;
    koff += 128;
  }
  {
    const int o1 = koff + 64;
    RDA4(pak0, pak1, 0); RDB2(bf0, pbk0, pbk1, 0);
    stage16(Ab0 + o1, ldsW + 65536); stage16(Ab1 + o1, ldsW + 73728);
    SB; BAR; LGK0; MQ16(acc0, 0, bf0); BAR;
    RDB2(bf1, pbk0, pbk1, 1);
    stage16(Ab2 + o1, ldsW + 81920); stage16(Ab3 + o1, ldsW + 90112);
    SB; BAR; LGK0; MQ16(acc0, 1, bf1); BAR;
    RDA4(pak0, pak1, 1);
    SB; BAR; LGK0; MQ16(acc1, 0, bf0); BAR;
    SB; BAR; MQ16(acc1, 1, bf1); VM0; BAR;
    RDA4(pak0b, pak1b, 0); RDB2(bf0, pbk0b, pbk1b, 0);
    SB; BAR; LGK0; MQ16(acc0, 0, bf0); BAR;
    RDB2(bf1, pbk0b, pbk1b, 1);
    SB; BAR; LGK0; MQ16(acc0, 1, bf1); BAR;
    RDA4(pak0b, pak1b, 1);
    SB; BAR; LGK0; MQ16(acc1, 0, bf0); BAR;
    SB; BAR; MQ16(acc1, 1, bf1); BAR;
  }

  const int colb = bn * 256 + wc * 64 + fr;
#pragma unroll
  for (int mh = 0; mh < 2; ++mh) {
    f32x4(&ac)[4][4] = mh ? acc1 : acc0;
    const int rowl = bm * 256 + wr * 128 + mh * 64 + fq * 4;
    if (o < 2) {
      const float* bp = o ? b1 : b0;
      u16* Cb = (u16*)(o ? C1 : C) + (size_t)z * (2048u * 1024u);
#pragma unroll
      for (int mf = 0; mf < 4; ++mf)
#pragma unroll
        for (int n = 0; n < 4; ++n) {
          const int c = colb + n * 16;
          const float bv = bp[c];
#pragma unroll
          for (int j = 0; j < 4; ++j)
            Cb[(size_t)(rowl + mf * 16 + j) * ldc + c] = f2bf(ac[mf][n][j] + bv);
        }
    } else {
      u16* Cb = (u16*)C2;  // vcT [8][1024][2048]
#pragma unroll
      for (int mf = 0; mf < 4; ++mf) {
        const int s_ = rowl + mf * 16;
#pragma unroll
        for (int n = 0; n < 4; ++n) {
          const int c = colb + n * 16;
          const float bv = b2[c];
          ushort4 ov;
          ov.x = f2bf(ac[mf][n][0] + bv);
          ov.y = f2bf(ac[mf][n][1] + bv);
          ov.z = f2bf(ac[mf][n][2] + bv);
          ov.w = f2bf(ac[mf][n][3] + bv);
          *(ushort4*)&Cb[((size_t)z * 1024 + c) * 2048 + s_] = ov;
        }
      }
    }
  }
}

// ======= 128x128/BK32 4-wave 2-phase core: scores (+vmeanred aux) & PV ======
// MODE 2: scores = qc kc^T /32 (bf16 out); bx>=2048 -> vmeanred aux.
// MODE 3: PV -> d_out scatter (fp32).
template <int MODE>
__global__ __launch_bounds__(256, 2) void gemm128(
    const u16* __restrict__ A, const u16* __restrict__ B, void* __restrict__ C,
    const int* __restrict__ nvp128A, const int* __restrict__ nvA,
    const int* __restrict__ idxA,
    const float* __restrict__ p0, const float* __restrict__ p1,
    float* __restrict__ p2,
    int K, int lda, int ldb, int ldc,
    size_t Az, size_t Bz, size_t Cz) {
  __shared__ __attribute__((aligned(16))) u16 lsA[2 * 128 * 32];
  __shared__ __attribute__((aligned(16))) u16 lsB[2 * 128 * 32];

  if constexpr (MODE == 2) {
    // aux region: vmeanred (8b x 4cq = 32 blocks)
    if (blockIdx.x >= 2048) {
      const int r2 = blockIdx.x - 2048;
      const int b = r2 & 7, cq = r2 >> 3;
      const int c = cq * 256 + threadIdx.x;
      float acc = p1[c];
#pragma unroll
      for (int i = 0; i < 8; ++i) acc += p0[((size_t)b * 8 + i) * 1024 + c];
      p2[b * 1024 + c] = acc;
      return;
    }
  }

  const int tid = threadIdx.x;
  const int lane = tid & 63;
  const int w = tid >> 6;      // 0..3
  const int wr = w >> 1, wc = w & 1;

  const int bx = blockIdx.x;
  const int z = bx & 7;
  const int r = bx >> 3;
  int bm, bn;
  if constexpr (MODE == 2) { bm = r >> 4; bn = r & 15; }   // 16 x 16
  else                     { bm = r >> 3; bn = r & 7; }    // 16 x 8

  const int nvp = nvp128A[z];
  if (bm * 128 >= nvp) return;
  if constexpr (MODE == 2) { if (bn * 128 >= nvp) return; }
  const int Kz = (MODE == 3) ? nvp : K;

  const u16* Ap = A + (size_t)z * Az;
  const u16* Bp = B + (size_t)z * Bz;

  const int srow = lane >> 2;
  const int scol = (lane & 3) * 8;
  const u16* Ag0 = Ap + (size_t)(bm * 128 + w * 32 + srow) * lda + scol;
  const u16* Ag1 = Ag0 + (size_t)16 * lda;
  const u16* Bg0 = Bp + (size_t)(bn * 128 + w * 32 + srow) * ldb + scol;
  const u16* Bg1 = Bg0 + (size_t)16 * ldb;
  u16* lA0 = &lsA[(w * 32) * 32];
  u16* lA1 = &lsA[(w * 32 + 16) * 32];
  u16* lB0 = &lsB[(w * 32) * 32];
  u16* lB1 = &lsB[(w * 32 + 16) * 32];

  const int arow = wr * 64 + (lane & 15);
  const int brow = wc * 64 + (lane & 15);
  const int ko = (lane >> 4) * 8;

  f32x4 acc[4][4] = {};

  auto compute = [&](int cur) {
    const u16* sA = lsA + cur * 4096;
    const u16* sB = lsB + cur * 4096;
    short8 af[4], bfr[4];
#pragma unroll
    for (int m = 0; m < 4; ++m)
      af[m] = *(const short8*)&sA[(arow + m * 16) * 32 + ko];
#pragma unroll
    for (int n = 0; n < 4; ++n)
      bfr[n] = *(const short8*)&sB[(brow + n * 16) * 32 + ko];
#pragma unroll
    for (int m = 0; m < 4; ++m)
#pragma unroll
      for (int n = 0; n < 4; ++n)
        acc[m][n] =
            __builtin_amdgcn_mfma_f32_16x16x32_bf16(af[m], bfr[n], acc[m][n], 0, 0, 0);
  };

  stage16(Ag0, lA0);
  stage16(Ag1, lA1);
  stage16(Bg0, lB0);
  stage16(Bg1, lB1);
  __syncthreads();

  int cur = 0;
  int k0 = 0;
  for (; k0 + 32 < Kz; k0 += 32) {
    const int off = (cur ^ 1) * 4096;
    const int kn = k0 + 32;
    stage16(Ag0 + kn, lA0 + off);
    stage16(Ag1 + kn, lA1 + off);
    stage16(Bg0 + kn, lB0 + off);
    stage16(Bg1 + kn, lB1 + off);
    compute(cur);
    __syncthreads();
    cur ^= 1;
  }
  compute(cur);

  const int col0 = bn * 128 + wc * 64 + (lane & 15);
  const int row0 = bm * 128 + wr * 64 + ((lane >> 4) << 2);

  if constexpr (MODE == 2) {
    u16* Cb = (u16*)C + (size_t)z * Cz;
#pragma unroll
    for (int m = 0; m < 4; ++m)
#pragma unroll
      for (int n = 0; n < 4; ++n) {
        const int c = col0 + n * 16;
#pragma unroll
        for (int j = 0; j < 4; ++j)
          Cb[(size_t)(row0 + m * 16 + j) * ldc + c] =
              f2bf(acc[m][n][j] * 0.03125f);
      }
  } else {  // MODE 3: scatter rows < nv via idx
    const int nv = nvA[z];
    const int* idxp = idxA + z * 2048;
    float* Ob = (float*)C;
#pragma unroll
    for (int m = 0; m < 4; ++m)
#pragma unroll
      for (int j = 0; j < 4; ++j) {
        const int rowc = row0 + m * 16 + j;
        if (rowc < nv) {
          const int gr = idxp[rowc];
          float* orow = Ob + ((size_t)z * 2048 + gr) * 1024;
#pragma unroll
          for (int n = 0; n < 4; ++n) orow[col0 + n * 16] = acc[m][n][j];
        }
      }
  }
}

// ---- merged: softmax (z=0) + bcast of vmean to masked rows (z=1) ----
__global__ __launch_bounds__(256) void softbc(u16* __restrict__ scores,
                                              const int* __restrict__ nvA,
                                              const int* __restrict__ nvp128A,
                                              const int* __restrict__ mask,
                                              const float* __restrict__ vmean,
                                              float* __restrict__ out) {
  const int b = blockIdx.y, row = blockIdx.x;
  if (blockIdx.z == 1) {
    if (mask[b * 2048 + row] != 0) return;
    const float4 vv = ((const float4*)(vmean + b * 1024))[threadIdx.x];
    ((float4*)(out + ((size_t)b * 2048 + row) * 1024))[threadIdx.x] = vv;
    return;
  }
  const int nv = nvA[b];
  if (row >= nv) return;
  const int nvp = nvp128A[b];
  const int t = threadIdx.x, lane = t & 63, w = t >> 6;
  u16* sc = scores + ((size_t)b * 2048 + row) * 2048;
  const int c0 = t * 8;
  float v[8];
  if (c0 < nvp) {
    const ushort4 h0 = *(const ushort4*)&sc[c0];
    const ushort4 h1 = *(const ushort4*)&sc[c0 + 4];
    v[0] = bf2f(h0.x); v[1] = bf2f(h0.y); v[2] = bf2f(h0.z); v[3] = bf2f(h0.w);
    v[4] = bf2f(h1.x); v[5] = bf2f(h1.y); v[6] = bf2f(h1.z); v[7] = bf2f(h1.w);
  } else {
#pragma unroll
    for (int i = 0; i < 8; ++i) v[i] = 0.f;
  }
  float lmax = -3.0e38f;
#pragma unroll
  for (int i = 0; i < 8; ++i)
    if (c0 + i < nv) lmax = fmaxf(lmax, v[i]);
#pragma unroll
  for (int off = 32; off >= 1; off >>= 1) lmax = fmaxf(lmax, __shfl_xor(lmax, off));
  __shared__ float red[8];
  if (lane == 0) red[w] = lmax;
  __syncthreads();
  const float bmax = fmaxf(fmaxf(red[0], red[1]), fmaxf(red[2], red[3]));
  float e[8];
  float lsum = 0.f;
#pragma unroll
  for (int i = 0; i < 8; ++i) {
    e[i] = (c0 + i < nv) ? __expf(v[i] - bmax) : 0.f;
    lsum += e[i];
  }
#pragma unroll
  for (int off = 32; off >= 1; off >>= 1) lsum += __shfl_xor(lsum, off);
  if (lane == 0) red[4 + w] = lsum;
  __syncthreads();
  const float inv = 1.0f / ((red[4] + red[5]) + (red[6] + red[7]));
  if (c0 < nvp) {
    ushort4 o0, o1;
    o0.x = f2bf(e[0] * inv); o0.y = f2bf(e[1] * inv);
    o0.z = f2bf(e[2] * inv); o0.w = f2bf(e[3] * inv);
    o1.x = f2bf(e[4] * inv); o1.y = f2bf(e[5] * inv);
    o1.z = f2bf(e[6] * inv); o1.w = f2bf(e[7] * inv);
    *(ushort4*)&sc[c0] = o0;
    *(ushort4*)&sc[c0 + 4] = o1;
  }
}

extern "C" void kernel_launch(void* const* d_in, const int* in_sizes, int n_in,
                              void* d_out, int out_size, void* d_ws, size_t ws_size,
                              hipStream_t stream) {
  const float* in_q = (const float*)d_in[0];
  const float* in_k = (const float*)d_in[1];
  const float* in_v = (const float*)d_in[2];
  const int* mask = (const int*)d_in[3];
  const float* Wq = (const float*)d_in[4];
  const float* bq = (const float*)d_in[5];
  const float* Wk = (const float*)d_in[6];
  const float* bk = (const float*)d_in[7];
  const float* Wv = (const float*)d_in[8];
  const float* bv = (const float*)d_in[9];

  char* ws = (char*)d_ws;
  const size_t SZ = (size_t)16384 * 1024 * 2;  // 32M bytes
  u16* qc = (u16*)(ws);
  u16* kc = (u16*)(ws + SZ);
  u16* vcT = (u16*)(ws + 2 * SZ);
  u16* Xc = (u16*)(ws + 3 * SZ);        // Xqc, Xkc, Xvc (32M each)
  u16* Xqc = Xc;
  u16* Xkc = Xc + (size_t)8 * 2048 * 1024;
  u16* Xvc = Xkc + (size_t)8 * 2048 * 1024;
  u16* scores = (u16*)(ws + 3 * SZ);    // overlays Xc after projections
  u16* WT = (u16*)(ws + 6 * SZ);        // WqT, WkT, WvT contiguous
  char* misc = ws + 6 * SZ + 6 * 1024 * 1024;
  int* idxA = (int*)misc;               // [8][2048] = 64KB
  int* nvA = idxA + 8 * 2048;
  int* nvp128A = nvA + 8;
  float* partial = (float*)(misc + 128 * 1024);  // [8][8][1024] = 256KB
  float* vmean = (float*)(misc + 384 * 1024);    // [8][1024] = 32KB
  float* vpart = (float*)(misc + 448 * 1024);    // [8][8][1024] = 256KB

  // 1) maskscan + weight transposes + colpart (one dispatch)
  scanwt<<<3336, 256, 0, stream>>>(mask, idxA, nvA, nvp128A, Wq, Wk, Wv, WT,
                                   in_v, partial);

  // 2) gather+convert, 4 rows/block
  compact3<<<dim3(512, 8, 3), 256, 0, stream>>>(in_q, in_k, in_v, idxA, nvA,
                                                Xqc, Xkc, Xvc);

  // 3) projections (256^2 core) + vpartk aux: 768 + 128 = 896 blocks
  gemm8p<<<896, 512, 0, stream>>>(
      Xqc, WT, qc, kc, vcT, bq, bk, bv, nvp128A, partial, Wv, vpart,
      1024, 1024, 1024, 1024);

  // 4) scores (128^2 2-phase core) + vmeanred aux: 2048 + 32 = 2080 blocks
  gemm128<2><<<2080, 256, 0, stream>>>(
      qc, kc, scores, nvp128A, nvA, idxA, vpart, bv, vmean,
      1024, 1024, 1024, 2048,
      (size_t)2048 * 1024, (size_t)2048 * 1024, (size_t)2048 * 2048);

  // 5) softmax (z=0) + bcast (z=1)
  softbc<<<dim3(2048, 8, 2), 256, 0, stream>>>(scores, nvA, nvp128A, mask,
                                               vmean, (float*)d_out);

  // 6) PV (128^2 2-phase core): 1024 blocks; K = nvp128[z]
  gemm128<3><<<1024, 256, 0, stream>>>(
      scores, vcT, d_out, nvp128A, nvA, idxA, nullptr, nullptr, nullptr,
      0, 2048, 2048, 1024,
      (size_t)2048 * 2048, (size_t)1024 * 2048, 0);
}